// Round 2
// baseline (1058.564 us; speedup 1.0000x reference)
//
#include <hip/hip_runtime.h>

#define NODES   10000
#define EDGES   320000
#define INF_    256
#define HIDF    128
#define NHEADS  4

// ---------------- degree / norm ----------------
__global__ void deg_kernel(const int* __restrict__ src, const int* __restrict__ dst,
                           int* __restrict__ deg_o, int* __restrict__ deg_i) {
    int e = blockIdx.x * blockDim.x + threadIdx.x;
    if (e < EDGES) {
        atomicAdd(&deg_o[src[e]], 1);
        atomicAdd(&deg_i[dst[e]], 1);
    }
}

__global__ void inv_kernel(const int* __restrict__ deg_o, const int* __restrict__ deg_i,
                           float* __restrict__ inv_o, float* __restrict__ inv_i) {
    int n = blockIdx.x * blockDim.x + threadIdx.x;
    if (n < NODES) {
        inv_o[n] = rsqrtf(fmaxf((float)deg_o[n], 1.0f));
        inv_i[n] = rsqrtf(fmaxf((float)deg_i[n], 1.0f));
    }
}

// ---------------- dense GEMM: Y[r,c] = (scale[r]*X[r,:]) @ W[:,c] ----------------
template<int KIN, int KOUT, int ROWS>
__global__ void gemm_scaled(const float* __restrict__ X, const float* __restrict__ scale,
                            const float* __restrict__ W, float* __restrict__ Y) {
    __shared__ float xs[ROWS][KIN];
    const int r0 = blockIdx.x * ROWS;
    for (int idx = threadIdx.x; idx < ROWS * KIN; idx += blockDim.x) {
        int r = idx / KIN, k = idx - r * KIN;
        int row = r0 + r;
        float v = 0.f;
        if (row < NODES) {
            v = X[row * KIN + k];
            if (scale) v *= scale[row];
        }
        xs[r][k] = v;
    }
    __syncthreads();
    for (int c = threadIdx.x; c < KOUT; c += blockDim.x) {
        float acc[ROWS];
#pragma unroll
        for (int r = 0; r < ROWS; ++r) acc[r] = 0.f;
        for (int k = 0; k < KIN; ++k) {
            float wv = W[k * KOUT + c];
#pragma unroll
            for (int r = 0; r < ROWS; ++r) acc[r] = fmaf(xs[r][k], wv, acc[r]);
        }
#pragma unroll
        for (int r = 0; r < ROWS; ++r) {
            int row = r0 + r;
            if (row < NODES) Y[row * KOUT + c] = acc[r];
        }
    }
}

// ---------------- edge scatter-add of F-wide feature rows ----------------
template<int F>
__global__ void scatter_add(const float* __restrict__ h, const int* __restrict__ src,
                            const int* __restrict__ dst, float* __restrict__ G) {
    int id = blockIdx.x * blockDim.x + threadIdx.x;
    int e = id / F;
    int f = id - e * F;
    if (e < EDGES) atomicAdd(&G[dst[e] * F + f], h[src[e] * F + f]);
}

// ---------------- GraphConv epilogue ----------------
__global__ void gc_finalize(const float* __restrict__ G, const float* __restrict__ inv_i,
                            const float* __restrict__ b, float* __restrict__ H, int do_relu) {
    int id = blockIdx.x * blockDim.x + threadIdx.x;
    if (id < NODES * HIDF) {
        int n = id >> 7, c = id & (HIDF - 1);
        float v = G[id] * inv_i[n] + b[c];
        if (do_relu) v = fmaxf(v, 0.f);
        H[id] = v;
    }
}

// ---------------- GAT: el/er projections (one wave per (n,h)) ----------------
__global__ void attn_proj(const float* __restrict__ Z, const float* __restrict__ attn_l,
                          const float* __restrict__ attn_r, float* __restrict__ el,
                          float* __restrict__ er) {
    int task = blockIdx.x * (blockDim.x / 64) + threadIdx.x / 64;
    int lane = threadIdx.x & 63;
    if (task >= NODES * NHEADS) return;
    int h = task & (NHEADS - 1);
    const float* zp = Z + (size_t)task * HIDF;  // [N][H*D]: task*D == n*H*D + h*D
    float a = 0.f, b = 0.f;
    for (int d = lane; d < HIDF; d += 64) {
        float zv = zp[d];
        a = fmaf(zv, attn_l[h * HIDF + d], a);
        b = fmaf(zv, attn_r[h * HIDF + d], b);
    }
    for (int off = 32; off; off >>= 1) {
        a += __shfl_down(a, off, 64);
        b += __shfl_down(b, off, 64);
    }
    if (lane == 0) { el[task] = a; er[task] = b; }
}

__global__ void neg_inf_init(float* __restrict__ m, int n) {
    int i = blockIdx.x * blockDim.x + threadIdx.x;
    if (i < n) m[i] = -INFINITY;
}

// ---------------- GAT: edge logits + segment max ----------------
__global__ void edge_logits(const int* __restrict__ src, const int* __restrict__ dst,
                            const float* __restrict__ el, const float* __restrict__ er,
                            float* __restrict__ ebuf, float* __restrict__ m) {
    int id = blockIdx.x * blockDim.x + threadIdx.x;
    if (id >= EDGES * NHEADS) return;
    int e = id >> 2, h = id & 3;
    float v = el[src[e] * NHEADS + h] + er[dst[e] * NHEADS + h];
    v = v > 0.f ? v : 0.2f * v;          // leaky_relu(0.2)
    ebuf[id] = v;
    float* addr = &m[dst[e] * NHEADS + h];
    if (v >= 0.f) atomicMax((int*)addr, __float_as_int(v));
    else          atomicMin((unsigned int*)addr, __float_as_uint(v));
}

// ---------------- GAT: exp + denom ----------------
__global__ void edge_exp(const int* __restrict__ dst, const float* __restrict__ m,
                         float* __restrict__ ebuf, float* __restrict__ denom) {
    int id = blockIdx.x * blockDim.x + threadIdx.x;
    if (id >= EDGES * NHEADS) return;
    int e = id >> 2, h = id & 3;
    float ex = expf(ebuf[id] - m[dst[e] * NHEADS + h]);
    ebuf[id] = ex;
    atomicAdd(&denom[dst[e] * NHEADS + h], ex);
}

// ---------------- GAT: weighted aggregation ----------------
__global__ void gat_agg(const int* __restrict__ src, const int* __restrict__ dst,
                        const float* __restrict__ ebuf, const float* __restrict__ denom,
                        const float* __restrict__ Z, float* __restrict__ G) {
    int id = blockIdx.x * blockDim.x + threadIdx.x;
    if (id >= EDGES * NHEADS * HIDF) return;
    int e = id >> 9;             // / 512
    int r = id & 511;
    int h = r >> 7;
    int dn = dst[e];
    float alpha = ebuf[e * NHEADS + h] / denom[dn * NHEADS + h];
    atomicAdd(&G[dn * 512 + r], alpha * Z[src[e] * 512 + r]);
}

// ---------------- GAT epilogue: +bg, mean over heads ----------------
__global__ void gat_finalize(const float* __restrict__ G, const float* __restrict__ bg,
                             float* __restrict__ H) {
    int id = blockIdx.x * blockDim.x + threadIdx.x;
    if (id < NODES * HIDF) {
        int n = id >> 7, d = id & (HIDF - 1);
        float v = G[n * 512 + d] + G[n * 512 + 128 + d] + G[n * 512 + 256 + d] + G[n * 512 + 384 + d];
        float bb = bg[d] + bg[128 + d] + bg[256 + d] + bg[384 + d];
        H[id] = 0.25f * (v + bb);
    }
}

// ---------------- GC3: per-row dot with W3 (one wave per row) ----------------
__global__ void rowdot(const float* __restrict__ H, const float* __restrict__ inv_o,
                       const float* __restrict__ w3, float* __restrict__ s) {
    int row = blockIdx.x * (blockDim.x / 64) + threadIdx.x / 64;
    int lane = threadIdx.x & 63;
    if (row >= NODES) return;
    float acc = 0.f;
    for (int k = lane; k < HIDF; k += 64) acc = fmaf(H[row * HIDF + k], w3[k], acc);
    for (int off = 32; off; off >>= 1) acc += __shfl_down(acc, off, 64);
    if (lane == 0) s[row] = acc * inv_o[row];
}

__global__ void scatter1(const int* __restrict__ src, const int* __restrict__ dst,
                         const float* __restrict__ s, float* __restrict__ agg3) {
    int e = blockIdx.x * blockDim.x + threadIdx.x;
    if (e < EDGES) atomicAdd(&agg3[dst[e]], s[src[e]]);
}

__global__ void final_k(const float* __restrict__ agg3, const float* __restrict__ inv_i,
                        const float* __restrict__ b3, float* __restrict__ out) {
    int n = blockIdx.x * blockDim.x + threadIdx.x;
    if (n < NODES) {
        float x = agg3[n] * inv_i[n] + b3[0];
        out[n] = 1.f / (1.f + expf(-x));
    }
}

extern "C" void kernel_launch(void* const* d_in, const int* in_sizes, int n_in,
                              void* d_out, int out_size, void* d_ws, size_t ws_size,
                              hipStream_t stream) {
    const float* feat   = (const float*)d_in[0];
    const int*   src    = (const int*)d_in[1];
    const int*   dst    = (const int*)d_in[2];
    const float* W1     = (const float*)d_in[3];
    const float* b1     = (const float*)d_in[4];
    const float* W2     = (const float*)d_in[5];
    const float* b2     = (const float*)d_in[6];
    const float* W3     = (const float*)d_in[7];
    const float* b3     = (const float*)d_in[8];
    const float* Wg     = (const float*)d_in[9];
    const float* attn_l = (const float*)d_in[10];
    const float* attn_r = (const float*)d_in[11];
    const float* bg     = (const float*)d_in[12];

    char* w = (char*)d_ws;
    auto alloc = [&](size_t bytes) { void* p = (void*)w; w += (bytes + 255) & ~(size_t)255; return p; };
    int*   deg_o = (int*)  alloc(NODES * 4);
    int*   deg_i = (int*)  alloc(NODES * 4);
    float* inv_o = (float*)alloc(NODES * 4);
    float* inv_i = (float*)alloc(NODES * 4);
    float* el    = (float*)alloc(NODES * NHEADS * 4);
    float* er    = (float*)alloc(NODES * NHEADS * 4);
    float* m     = (float*)alloc(NODES * NHEADS * 4);
    float* denom = (float*)alloc(NODES * NHEADS * 4);
    float* s1    = (float*)alloc(NODES * 4);
    float* agg3  = (float*)alloc(NODES * 4);
    float* H     = (float*)alloc((size_t)NODES * HIDF * 4);            // node features
    float* Z     = (float*)alloc((size_t)NODES * NHEADS * HIDF * 4);   // gemm out / z
    float* G     = (float*)alloc((size_t)NODES * NHEADS * HIDF * 4);   // aggregation buf
    float* ebuf  = (float*)alloc((size_t)EDGES * NHEADS * 4);

    // degrees + norms (graph fixed across layers)
    hipMemsetAsync(deg_o, 0, NODES * 4, stream);
    hipMemsetAsync(deg_i, 0, NODES * 4, stream);
    deg_kernel<<<(EDGES + 255) / 256, 256, 0, stream>>>(src, dst, deg_o, deg_i);
    inv_kernel<<<(NODES + 255) / 256, 256, 0, stream>>>(deg_o, deg_i, inv_o, inv_i);

    const int GEMM_BLOCKS = (NODES + 7) / 8;  // ROWS=8

    // ---- GraphConv 1: feat[256] -> 128, relu ----
    gemm_scaled<INF_, HIDF, 8><<<GEMM_BLOCKS, 128, 0, stream>>>(feat, inv_o, W1, Z);
    hipMemsetAsync(G, 0, (size_t)NODES * HIDF * 4, stream);
    scatter_add<HIDF><<<(EDGES * HIDF + 255) / 256, 256, 0, stream>>>(Z, src, dst, G);
    gc_finalize<<<(NODES * HIDF + 255) / 256, 256, 0, stream>>>(G, inv_i, b1, H, 1);

    // ---- GraphConv 2: 128 -> 128, relu ----
    gemm_scaled<HIDF, HIDF, 8><<<GEMM_BLOCKS, 128, 0, stream>>>(H, inv_o, W2, Z);
    hipMemsetAsync(G, 0, (size_t)NODES * HIDF * 4, stream);
    scatter_add<HIDF><<<(EDGES * HIDF + 255) / 256, 256, 0, stream>>>(Z, src, dst, G);
    gc_finalize<<<(NODES * HIDF + 255) / 256, 256, 0, stream>>>(G, inv_i, b2, H, 1);

    // ---- GATConv: z = H @ Wg [N, 512] ----
    gemm_scaled<HIDF, NHEADS * HIDF, 8><<<GEMM_BLOCKS, 512, 0, stream>>>(H, nullptr, Wg, Z);
    attn_proj<<<(NODES * NHEADS + 3) / 4, 256, 0, stream>>>(Z, attn_l, attn_r, el, er);
    neg_inf_init<<<(NODES * NHEADS + 255) / 256, 256, 0, stream>>>(m, NODES * NHEADS);
    edge_logits<<<(EDGES * NHEADS + 255) / 256, 256, 0, stream>>>(src, dst, el, er, ebuf, m);
    hipMemsetAsync(denom, 0, NODES * NHEADS * 4, stream);
    edge_exp<<<(EDGES * NHEADS + 255) / 256, 256, 0, stream>>>(dst, m, ebuf, denom);
    hipMemsetAsync(G, 0, (size_t)NODES * NHEADS * HIDF * 4, stream);
    gat_agg<<<(EDGES * NHEADS * HIDF) / 256, 256, 0, stream>>>(src, dst, ebuf, denom, Z, G);
    gat_finalize<<<(NODES * HIDF + 255) / 256, 256, 0, stream>>>(G, bg, H);

    // ---- GraphConv 3: 128 -> 1, sigmoid ----
    rowdot<<<(NODES * 64 + 255) / 256, 256, 0, stream>>>(H, inv_o, W3, s1);
    hipMemsetAsync(agg3, 0, NODES * 4, stream);
    scatter1<<<(EDGES + 255) / 256, 256, 0, stream>>>(src, dst, s1, agg3);
    final_k<<<(NODES + 255) / 256, 256, 0, stream>>>(agg3, inv_i, b3, (float*)d_out);
}

// Round 3
// 400.468 us; speedup vs baseline: 2.6433x; 2.6433x over previous
//
#include <hip/hip_runtime.h>

#define NODES   10000
#define EDGES   320000
#define INF_    256
#define HIDF    128
#define NHEADS  4
#define SCAN_T  1024
#define SCAN_C  ((NODES + SCAN_T - 1) / SCAN_T)   // 10

// ---------------- degree ----------------
__global__ void deg_kernel(const int* __restrict__ src, const int* __restrict__ dst,
                           int* __restrict__ deg_o, int* __restrict__ deg_i) {
    int e = blockIdx.x * blockDim.x + threadIdx.x;
    if (e < EDGES) {
        atomicAdd(&deg_o[src[e]], 1);
        atomicAdd(&deg_i[dst[e]], 1);
    }
}

__global__ void inv_kernel(const int* __restrict__ deg_o, const int* __restrict__ deg_i,
                           float* __restrict__ inv_o, float* __restrict__ inv_i) {
    int n = blockIdx.x * blockDim.x + threadIdx.x;
    if (n < NODES) {
        inv_o[n] = rsqrtf(fmaxf((float)deg_o[n], 1.0f));
        inv_i[n] = rsqrtf(fmaxf((float)deg_i[n], 1.0f));
    }
}

// ---------------- exclusive scan of deg_i -> rowptr (and cursor copy) ----------------
__global__ void scan_kernel(const int* __restrict__ deg_i, int* __restrict__ rowptr,
                            int* __restrict__ cursor) {
    __shared__ int part[SCAN_T];
    int t = threadIdx.x;
    int base = t * SCAN_C;
    int local[SCAN_C];
    int s = 0;
    for (int j = 0; j < SCAN_C; ++j) {
        int idx = base + j;
        int v = idx < NODES ? deg_i[idx] : 0;
        local[j] = s;
        s += v;
    }
    part[t] = s;
    __syncthreads();
    for (int off = 1; off < SCAN_T; off <<= 1) {
        int v = (t >= off) ? part[t - off] : 0;
        __syncthreads();
        part[t] += v;
        __syncthreads();
    }
    int offs = (t > 0) ? part[t - 1] : 0;
    for (int j = 0; j < SCAN_C; ++j) {
        int idx = base + j;
        if (idx < NODES) {
            int r = offs + local[j];
            rowptr[idx] = r;
            cursor[idx] = r;
        }
    }
    if (t == SCAN_T - 1) rowptr[NODES] = part[SCAN_T - 1];
}

__global__ void csr_fill(const int* __restrict__ src, const int* __restrict__ dst,
                         int* __restrict__ cursor, int* __restrict__ csr_src) {
    int e = blockIdx.x * blockDim.x + threadIdx.x;
    if (e < EDGES) {
        int pos = atomicAdd(&cursor[dst[e]], 1);
        csr_src[pos] = src[e];
    }
}

// ---------------- dense GEMM: Y[r,c] = (scale[r]*X[r,:]) @ W[:,c] ----------------
template<int KIN, int KOUT, int ROWS>
__global__ void gemm_scaled(const float* __restrict__ X, const float* __restrict__ scale,
                            const float* __restrict__ W, float* __restrict__ Y) {
    __shared__ float xs[ROWS][KIN];
    const int r0 = blockIdx.x * ROWS;
    for (int idx = threadIdx.x; idx < ROWS * KIN; idx += blockDim.x) {
        int r = idx / KIN, k = idx - r * KIN;
        int row = r0 + r;
        float v = 0.f;
        if (row < NODES) {
            v = X[row * KIN + k];
            if (scale) v *= scale[row];
        }
        xs[r][k] = v;
    }
    __syncthreads();
    for (int c = threadIdx.x; c < KOUT; c += blockDim.x) {
        float acc[ROWS];
#pragma unroll
        for (int r = 0; r < ROWS; ++r) acc[r] = 0.f;
        for (int k = 0; k < KIN; ++k) {
            float wv = W[k * KOUT + c];
#pragma unroll
            for (int r = 0; r < ROWS; ++r) acc[r] = fmaf(xs[r][k], wv, acc[r]);
        }
#pragma unroll
        for (int r = 0; r < ROWS; ++r) {
            int row = r0 + r;
            if (row < NODES) Y[row * KOUT + c] = acc[r];
        }
    }
}

// ---------------- GraphConv aggregation: dst-centric gather + fused epilogue ----------------
__global__ void gc_gather(const int* __restrict__ rowptr, const int* __restrict__ csr_src,
                          const float* __restrict__ Z, const float* __restrict__ inv_i,
                          const float* __restrict__ b, float* __restrict__ H, int do_relu) {
    int n = blockIdx.x;
    int f = threadIdx.x;  // 128 threads
    int beg = rowptr[n], end = rowptr[n + 1];
    float acc = 0.f;
    for (int i = beg; i < end; ++i) {
        acc += Z[csr_src[i] * HIDF + f];
    }
    float v = acc * inv_i[n] + b[f];
    if (do_relu) v = fmaxf(v, 0.f);
    H[n * HIDF + f] = v;
}

// ---------------- GAT: el/er projections (one wave per (n,h)) ----------------
__global__ void attn_proj(const float* __restrict__ Z, const float* __restrict__ attn_l,
                          const float* __restrict__ attn_r, float* __restrict__ el,
                          float* __restrict__ er) {
    int task = blockIdx.x * (blockDim.x / 64) + threadIdx.x / 64;
    int lane = threadIdx.x & 63;
    if (task >= NODES * NHEADS) return;
    int h = task & (NHEADS - 1);
    const float* zp = Z + (size_t)task * HIDF;  // [N][H*D]: task*D == n*H*D + h*D
    float a = 0.f, b = 0.f;
    for (int d = lane; d < HIDF; d += 64) {
        float zv = zp[d];
        a = fmaf(zv, attn_l[h * HIDF + d], a);
        b = fmaf(zv, attn_r[h * HIDF + d], b);
    }
    for (int off = 32; off; off >>= 1) {
        a += __shfl_down(a, off, 64);
        b += __shfl_down(b, off, 64);
    }
    if (lane == 0) { el[task] = a; er[task] = b; }
}

// ---------------- GAT: fused online-softmax aggregation, per-node ----------------
// block = 512 threads: t = h*128 + d. Online softmax over incoming edges.
__global__ void gat_fused(const int* __restrict__ rowptr, const int* __restrict__ csr_src,
                          const float* __restrict__ el, const float* __restrict__ er,
                          const float* __restrict__ Z, const float* __restrict__ bg,
                          float* __restrict__ H) {
    __shared__ float red[NHEADS * HIDF];
    int n = blockIdx.x;
    int t = threadIdx.x;
    int h = t >> 7;
    int d = t & (HIDF - 1);
    float er_n = er[n * NHEADS + h];
    int beg = rowptr[n], end = rowptr[n + 1];
    float m = -INFINITY, den = 0.f, acc = 0.f;
    for (int i = beg; i < end; ++i) {
        int s = csr_src[i];
        float logit = el[s * NHEADS + h] + er_n;
        logit = logit > 0.f ? logit : 0.2f * logit;  // leaky_relu(0.2)
        if (logit > m) {
            float c = __expf(m - logit);  // exp(-inf)=0 on first edge
            acc *= c;
            den *= c;
            m = logit;
        }
        float p = __expf(logit - m);
        den += p;
        acc = fmaf(p, Z[(size_t)s * (NHEADS * HIDF) + t], acc);
    }
    float o = (den > 0.f ? acc / den : 0.f) + bg[t];
    red[t] = o;
    __syncthreads();
    if (t < HIDF) {
        H[n * HIDF + t] = 0.25f * (red[t] + red[t + 128] + red[t + 256] + red[t + 384]);
    }
}

// ---------------- GC3: per-row dot with W3 (one wave per row) ----------------
__global__ void rowdot(const float* __restrict__ H, const float* __restrict__ inv_o,
                       const float* __restrict__ w3, float* __restrict__ s) {
    int row = blockIdx.x * (blockDim.x / 64) + threadIdx.x / 64;
    int lane = threadIdx.x & 63;
    if (row >= NODES) return;
    float acc = 0.f;
    for (int k = lane; k < HIDF; k += 64) acc = fmaf(H[row * HIDF + k], w3[k], acc);
    for (int off = 32; off; off >>= 1) acc += __shfl_down(acc, off, 64);
    if (lane == 0) s[row] = acc * inv_o[row];
}

// ---------------- GC3 gather + sigmoid ----------------
__global__ void gc3_gather(const int* __restrict__ rowptr, const int* __restrict__ csr_src,
                           const float* __restrict__ s1, const float* __restrict__ inv_i,
                           const float* __restrict__ b3, float* __restrict__ out) {
    int n = blockIdx.x * blockDim.x + threadIdx.x;
    if (n >= NODES) return;
    int beg = rowptr[n], end = rowptr[n + 1];
    float acc = 0.f;
    for (int i = beg; i < end; ++i) acc += s1[csr_src[i]];
    float x = acc * inv_i[n] + b3[0];
    out[n] = 1.f / (1.f + __expf(-x));
}

extern "C" void kernel_launch(void* const* d_in, const int* in_sizes, int n_in,
                              void* d_out, int out_size, void* d_ws, size_t ws_size,
                              hipStream_t stream) {
    const float* feat   = (const float*)d_in[0];
    const int*   src    = (const int*)d_in[1];
    const int*   dst    = (const int*)d_in[2];
    const float* W1     = (const float*)d_in[3];
    const float* b1     = (const float*)d_in[4];
    const float* W2     = (const float*)d_in[5];
    const float* b2     = (const float*)d_in[6];
    const float* W3     = (const float*)d_in[7];
    const float* b3     = (const float*)d_in[8];
    const float* Wg     = (const float*)d_in[9];
    const float* attn_l = (const float*)d_in[10];
    const float* attn_r = (const float*)d_in[11];
    const float* bg     = (const float*)d_in[12];

    char* w = (char*)d_ws;
    auto alloc = [&](size_t bytes) { void* p = (void*)w; w += (bytes + 255) & ~(size_t)255; return p; };
    int*   deg_o   = (int*)  alloc(NODES * 4);
    int*   deg_i   = (int*)  alloc(NODES * 4);
    float* inv_o   = (float*)alloc(NODES * 4);
    float* inv_i   = (float*)alloc(NODES * 4);
    int*   rowptr  = (int*)  alloc((NODES + 1) * 4);
    int*   cursor  = (int*)  alloc(NODES * 4);
    int*   csr_src = (int*)  alloc((size_t)EDGES * 4);
    float* el      = (float*)alloc(NODES * NHEADS * 4);
    float* er      = (float*)alloc(NODES * NHEADS * 4);
    float* s1      = (float*)alloc(NODES * 4);
    float* H       = (float*)alloc((size_t)NODES * HIDF * 4);
    float* H2      = (float*)alloc((size_t)NODES * HIDF * 4);
    float* Z       = (float*)alloc((size_t)NODES * NHEADS * HIDF * 4);

    // ---- graph preprocessing: degrees, norms, dst-CSR ----
    hipMemsetAsync(deg_o, 0, NODES * 4, stream);
    hipMemsetAsync(deg_i, 0, NODES * 4, stream);
    deg_kernel<<<(EDGES + 255) / 256, 256, 0, stream>>>(src, dst, deg_o, deg_i);
    inv_kernel<<<(NODES + 255) / 256, 256, 0, stream>>>(deg_o, deg_i, inv_o, inv_i);
    scan_kernel<<<1, SCAN_T, 0, stream>>>(deg_i, rowptr, cursor);
    csr_fill<<<(EDGES + 255) / 256, 256, 0, stream>>>(src, dst, cursor, csr_src);

    const int GEMM_BLOCKS = (NODES + 7) / 8;  // ROWS=8

    // ---- GraphConv 1: feat[256] -> 128, relu ----
    gemm_scaled<INF_, HIDF, 8><<<GEMM_BLOCKS, 128, 0, stream>>>(feat, inv_o, W1, Z);
    gc_gather<<<NODES, HIDF, 0, stream>>>(rowptr, csr_src, Z, inv_i, b1, H, 1);

    // ---- GraphConv 2: 128 -> 128, relu ----
    gemm_scaled<HIDF, HIDF, 8><<<GEMM_BLOCKS, 128, 0, stream>>>(H, inv_o, W2, Z);
    gc_gather<<<NODES, HIDF, 0, stream>>>(rowptr, csr_src, Z, inv_i, b2, H2, 1);

    // ---- GATConv: z = H2 @ Wg [N, 512]; fused edge-softmax + aggregation ----
    gemm_scaled<HIDF, NHEADS * HIDF, 8><<<GEMM_BLOCKS, 512, 0, stream>>>(H2, nullptr, Wg, Z);
    attn_proj<<<(NODES * NHEADS + 3) / 4, 256, 0, stream>>>(Z, attn_l, attn_r, el, er);
    gat_fused<<<NODES, NHEADS * HIDF, 0, stream>>>(rowptr, csr_src, el, er, Z, bg, H);

    // ---- GraphConv 3: 128 -> 1, sigmoid ----
    rowdot<<<(NODES * 64 + 255) / 256, 256, 0, stream>>>(H, inv_o, W3, s1);
    gc3_gather<<<(NODES + 255) / 256, 256, 0, stream>>>(rowptr, csr_src, s1, inv_i, b3, (float*)d_out);
}

// Round 4
// 285.735 us; speedup vs baseline: 3.7047x; 1.4015x over previous
//
#include <hip/hip_runtime.h>
#include <hip/hip_bf16.h>

#define NODES   10000
#define EDGES   320000
#define INF_    256
#define HIDF    128
#define NHEADS  4
#define SCAN_T  1024
#define SCAN_C  ((NODES + SCAN_T - 1) / SCAN_T)   // 10

__device__ __forceinline__ float bf_lo(unsigned int z) { return __uint_as_float(z << 16); }
__device__ __forceinline__ float bf_hi(unsigned int z) { return __uint_as_float(z & 0xffff0000u); }

// ---------------- degree ----------------
__global__ void deg_kernel(const int* __restrict__ src, const int* __restrict__ dst,
                           int* __restrict__ deg_o, int* __restrict__ deg_i) {
    int e = blockIdx.x * blockDim.x + threadIdx.x;
    if (e < EDGES) {
        atomicAdd(&deg_o[src[e]], 1);
        atomicAdd(&deg_i[dst[e]], 1);
    }
}

__global__ void inv_kernel(const int* __restrict__ deg_o, const int* __restrict__ deg_i,
                           float* __restrict__ inv_o, float* __restrict__ inv_i) {
    int n = blockIdx.x * blockDim.x + threadIdx.x;
    if (n < NODES) {
        inv_o[n] = rsqrtf(fmaxf((float)deg_o[n], 1.0f));
        inv_i[n] = rsqrtf(fmaxf((float)deg_i[n], 1.0f));
    }
}

// ---------------- exclusive scan of deg_i -> rowptr (and cursor copy) ----------------
__global__ void scan_kernel(const int* __restrict__ deg_i, int* __restrict__ rowptr,
                            int* __restrict__ cursor) {
    __shared__ int part[SCAN_T];
    int t = threadIdx.x;
    int base = t * SCAN_C;
    int local[SCAN_C];
    int s = 0;
    for (int j = 0; j < SCAN_C; ++j) {
        int idx = base + j;
        int v = idx < NODES ? deg_i[idx] : 0;
        local[j] = s;
        s += v;
    }
    part[t] = s;
    __syncthreads();
    for (int off = 1; off < SCAN_T; off <<= 1) {
        int v = (t >= off) ? part[t - off] : 0;
        __syncthreads();
        part[t] += v;
        __syncthreads();
    }
    int offs = (t > 0) ? part[t - 1] : 0;
    for (int j = 0; j < SCAN_C; ++j) {
        int idx = base + j;
        if (idx < NODES) {
            int r = offs + local[j];
            rowptr[idx] = r;
            cursor[idx] = r;
        }
    }
    if (t == SCAN_T - 1) rowptr[NODES] = part[SCAN_T - 1];
}

__global__ void csr_fill(const int* __restrict__ src, const int* __restrict__ dst,
                         int* __restrict__ cursor, int* __restrict__ csr_src) {
    int e = blockIdx.x * blockDim.x + threadIdx.x;
    if (e < EDGES) {
        int pos = atomicAdd(&cursor[dst[e]], 1);
        csr_src[pos] = src[e];
    }
}

// ---------------- dense GEMM: Y[r,c] = bf16((scale[r]*X[r,:]) @ W[:,c]) ----------------
template<int KIN, int KOUT, int ROWS>
__global__ void gemm_scaled(const float* __restrict__ X, const float* __restrict__ scale,
                            const float* __restrict__ W, __hip_bfloat16* __restrict__ Y) {
    __shared__ float xs[ROWS][KIN];
    const int r0 = blockIdx.x * ROWS;
    for (int idx = threadIdx.x; idx < ROWS * KIN; idx += blockDim.x) {
        int r = idx / KIN, k = idx - r * KIN;
        int row = r0 + r;
        float v = 0.f;
        if (row < NODES) {
            v = X[row * KIN + k];
            if (scale) v *= scale[row];
        }
        xs[r][k] = v;
    }
    __syncthreads();
    for (int c = threadIdx.x; c < KOUT; c += blockDim.x) {
        float acc[ROWS];
#pragma unroll
        for (int r = 0; r < ROWS; ++r) acc[r] = 0.f;
        for (int k = 0; k < KIN; ++k) {
            float wv = W[k * KOUT + c];
#pragma unroll
            for (int r = 0; r < ROWS; ++r) acc[r] = fmaf(xs[r][k], wv, acc[r]);
        }
#pragma unroll
        for (int r = 0; r < ROWS; ++r) {
            int row = r0 + r;
            if (row < NODES) Y[row * KOUT + c] = __float2bfloat16(acc[r]);
        }
    }
}

// ---------------- GraphConv aggregation: dst gather (bf16 in) + fused epilogue ----------------
// one wave per node; each lane owns 2 columns (one dword of bf16x2)
__global__ void gc_gather(const int* __restrict__ rowptr, const int* __restrict__ csr_src,
                          const __hip_bfloat16* __restrict__ Zb, const float* __restrict__ inv_i,
                          const float* __restrict__ b, float* __restrict__ H, int do_relu) {
    int n = blockIdx.x;
    int l = threadIdx.x;     // 64
    int beg = rowptr[n], end = rowptr[n + 1];
    float a0 = 0.f, a1 = 0.f;
#pragma unroll 4
    for (int i = beg; i < end; ++i) {
        int s = csr_src[i];
        unsigned int z = *(const unsigned int*)&Zb[s * HIDF + 2 * l];
        a0 += bf_lo(z);
        a1 += bf_hi(z);
    }
    float sc = inv_i[n];
    float v0 = a0 * sc + b[2 * l];
    float v1 = a1 * sc + b[2 * l + 1];
    if (do_relu) { v0 = fmaxf(v0, 0.f); v1 = fmaxf(v1, 0.f); }
    H[n * HIDF + 2 * l] = v0;
    H[n * HIDF + 2 * l + 1] = v1;
}

// ---------------- fold attn vectors through Wg: WL[k][h] = sum_d Wg[k, h*128+d]*attn_l[h,d]
__global__ void attn_w_k(const float* __restrict__ Wg, const float* __restrict__ attn_l,
                         const float* __restrict__ attn_r, float* __restrict__ WL,
                         float* __restrict__ WR) {
    int id = threadIdx.x;  // 512 = 128*4
    int k = id >> 2, h = id & 3;
    float a = 0.f, b = 0.f;
    for (int d = 0; d < HIDF; ++d) {
        float w = Wg[k * (NHEADS * HIDF) + h * HIDF + d];
        a = fmaf(w, attn_l[h * HIDF + d], a);
        b = fmaf(w, attn_r[h * HIDF + d], b);
    }
    WL[id] = a;
    WR[id] = b;
}

// ---------------- el/er = H2 @ WL / H2 @ WR   ([N,4] each) ----------------
__global__ void el_er_k(const float* __restrict__ H2, const float* __restrict__ WL,
                        const float* __restrict__ WR, float* __restrict__ el,
                        float* __restrict__ er) {
    int id = blockIdx.x * blockDim.x + threadIdx.x;  // N*4
    if (id >= NODES * NHEADS) return;
    int n = id >> 2, h = id & 3;
    float a = 0.f, b = 0.f;
    for (int k = 0; k < HIDF; ++k) {
        float x = H2[n * HIDF + k];
        a = fmaf(x, WL[k * NHEADS + h], a);
        b = fmaf(x, WR[k * NHEADS + h], b);
    }
    el[id] = a;
    er[id] = b;
}

// ---------------- edge softmax: alpha per (head, csr-slot), wave per (node, head) ----------------
__global__ void alpha_k(const int* __restrict__ rowptr, const int* __restrict__ csr_src,
                        const float* __restrict__ el, const float* __restrict__ er,
                        float* __restrict__ aw /*[4][EDGES]*/) {
    int n = blockIdx.x;
    int h = threadIdx.x >> 6;   // wave id = head
    int lane = threadIdx.x & 63;
    int beg = rowptr[n], end = rowptr[n + 1];
    float ern = er[n * NHEADS + h];
    // pass 1: max
    float m = -INFINITY;
    for (int i = beg + lane; i < end; i += 64) {
        float lg = el[csr_src[i] * NHEADS + h] + ern;
        lg = lg > 0.f ? lg : 0.2f * lg;
        m = fmaxf(m, lg);
    }
#pragma unroll
    for (int off = 32; off; off >>= 1) m = fmaxf(m, __shfl_xor(m, off, 64));
    // pass 2: exp + sum (store unnormalized)
    float den = 0.f;
    for (int i = beg + lane; i < end; i += 64) {
        float lg = el[csr_src[i] * NHEADS + h] + ern;
        lg = lg > 0.f ? lg : 0.2f * lg;
        float ex = __expf(lg - m);
        aw[h * EDGES + i] = ex;
        den += ex;
    }
#pragma unroll
    for (int off = 32; off; off >>= 1) den += __shfl_xor(den, off, 64);
    float rden = den > 0.f ? 1.f / den : 0.f;
    // pass 3: normalize
    for (int i = beg + lane; i < end; i += 64) {
        aw[h * EDGES + i] *= rden;
    }
}

// ---------------- GAT aggregation: out[n,h,:] = sum_i alpha * Z[src], + bias, head-mean ----------------
// 256 threads per node: t = h*64 + dd, columns (h*128 + 2dd, +1)
__global__ void gat_agg(const int* __restrict__ rowptr, const int* __restrict__ csr_src,
                        const float* __restrict__ aw, const __hip_bfloat16* __restrict__ Zgb,
                        const float* __restrict__ bg, float* __restrict__ H) {
    __shared__ float red[NHEADS * HIDF];
    int n = blockIdx.x;
    int t = threadIdx.x;        // 256
    int h = t >> 6;
    int dd = t & 63;
    int c = h * HIDF + 2 * dd;
    int beg = rowptr[n], end = rowptr[n + 1];
    float a0 = 0.f, a1 = 0.f;
#pragma unroll 2
    for (int i = beg; i < end; ++i) {
        int s = csr_src[i];
        float a = aw[h * EDGES + i];
        unsigned int z = *(const unsigned int*)&Zgb[s * (NHEADS * HIDF) + c];
        a0 = fmaf(a, bf_lo(z), a0);
        a1 = fmaf(a, bf_hi(z), a1);
    }
    red[c] = a0;
    red[c + 1] = a1;
    __syncthreads();
    if (t < HIDF) {
        float v = red[t] + red[t + 128] + red[t + 256] + red[t + 384]
                + bg[t] + bg[t + 128] + bg[t + 256] + bg[t + 384];
        H[n * HIDF + t] = 0.25f * v;
    }
}

// ---------------- GC3: per-row dot with W3 (one wave per row) ----------------
__global__ void rowdot(const float* __restrict__ H, const float* __restrict__ inv_o,
                       const float* __restrict__ w3, float* __restrict__ s) {
    int row = blockIdx.x * (blockDim.x / 64) + threadIdx.x / 64;
    int lane = threadIdx.x & 63;
    if (row >= NODES) return;
    float acc = 0.f;
    for (int k = lane; k < HIDF; k += 64) acc = fmaf(H[row * HIDF + k], w3[k], acc);
    for (int off = 32; off; off >>= 1) acc += __shfl_down(acc, off, 64);
    if (lane == 0) s[row] = acc * inv_o[row];
}

// ---------------- GC3 gather + sigmoid ----------------
__global__ void gc3_gather(const int* __restrict__ rowptr, const int* __restrict__ csr_src,
                           const float* __restrict__ s1, const float* __restrict__ inv_i,
                           const float* __restrict__ b3, float* __restrict__ out) {
    int n = blockIdx.x * blockDim.x + threadIdx.x;
    if (n >= NODES) return;
    int beg = rowptr[n], end = rowptr[n + 1];
    float acc = 0.f;
    for (int i = beg; i < end; ++i) acc += s1[csr_src[i]];
    float x = acc * inv_i[n] + b3[0];
    out[n] = 1.f / (1.f + __expf(-x));
}

extern "C" void kernel_launch(void* const* d_in, const int* in_sizes, int n_in,
                              void* d_out, int out_size, void* d_ws, size_t ws_size,
                              hipStream_t stream) {
    const float* feat   = (const float*)d_in[0];
    const int*   src    = (const int*)d_in[1];
    const int*   dst    = (const int*)d_in[2];
    const float* W1     = (const float*)d_in[3];
    const float* b1     = (const float*)d_in[4];
    const float* W2     = (const float*)d_in[5];
    const float* b2     = (const float*)d_in[6];
    const float* W3     = (const float*)d_in[7];
    const float* b3     = (const float*)d_in[8];
    const float* Wg     = (const float*)d_in[9];
    const float* attn_l = (const float*)d_in[10];
    const float* attn_r = (const float*)d_in[11];
    const float* bg     = (const float*)d_in[12];

    char* w = (char*)d_ws;
    auto alloc = [&](size_t bytes) { void* p = (void*)w; w += (bytes + 255) & ~(size_t)255; return p; };
    int*   deg_o   = (int*)  alloc(NODES * 4);
    int*   deg_i   = (int*)  alloc(NODES * 4);
    float* inv_o   = (float*)alloc(NODES * 4);
    float* inv_i   = (float*)alloc(NODES * 4);
    int*   rowptr  = (int*)  alloc((NODES + 1) * 4);
    int*   cursor  = (int*)  alloc(NODES * 4);
    int*   csr_src = (int*)  alloc((size_t)EDGES * 4);
    float* el      = (float*)alloc(NODES * NHEADS * 4);
    float* er      = (float*)alloc(NODES * NHEADS * 4);
    float* WL      = (float*)alloc(HIDF * NHEADS * 4);
    float* WR      = (float*)alloc(HIDF * NHEADS * 4);
    float* s1      = (float*)alloc(NODES * 4);
    float* H       = (float*)alloc((size_t)NODES * HIDF * 4);
    float* H2      = (float*)alloc((size_t)NODES * HIDF * 4);
    float* aw      = (float*)alloc((size_t)NHEADS * EDGES * 4);
    __hip_bfloat16* Zb  = (__hip_bfloat16*)alloc((size_t)NODES * HIDF * 2);
    __hip_bfloat16* Zgb = (__hip_bfloat16*)alloc((size_t)NODES * NHEADS * HIDF * 2);

    // ---- graph preprocessing: degrees, norms, dst-CSR ----
    hipMemsetAsync(deg_o, 0, NODES * 4, stream);
    hipMemsetAsync(deg_i, 0, NODES * 4, stream);
    deg_kernel<<<(EDGES + 255) / 256, 256, 0, stream>>>(src, dst, deg_o, deg_i);
    inv_kernel<<<(NODES + 255) / 256, 256, 0, stream>>>(deg_o, deg_i, inv_o, inv_i);
    scan_kernel<<<1, SCAN_T, 0, stream>>>(deg_i, rowptr, cursor);
    csr_fill<<<(EDGES + 255) / 256, 256, 0, stream>>>(src, dst, cursor, csr_src);

    const int GEMM_BLOCKS = (NODES + 7) / 8;  // ROWS=8

    // ---- GraphConv 1: feat[256] -> 128, relu ----
    gemm_scaled<INF_, HIDF, 8><<<GEMM_BLOCKS, 128, 0, stream>>>(feat, inv_o, W1, Zb);
    gc_gather<<<NODES, 64, 0, stream>>>(rowptr, csr_src, Zb, inv_i, b1, H, 1);

    // ---- GraphConv 2: 128 -> 128, relu ----
    gemm_scaled<HIDF, HIDF, 8><<<GEMM_BLOCKS, 128, 0, stream>>>(H, inv_o, W2, Zb);
    gc_gather<<<NODES, 64, 0, stream>>>(rowptr, csr_src, Zb, inv_i, b2, H2, 1);

    // ---- GATConv ----
    attn_w_k<<<1, 512, 0, stream>>>(Wg, attn_l, attn_r, WL, WR);
    el_er_k<<<(NODES * NHEADS + 255) / 256, 256, 0, stream>>>(H2, WL, WR, el, er);
    gemm_scaled<HIDF, NHEADS * HIDF, 8><<<GEMM_BLOCKS, 512, 0, stream>>>(H2, nullptr, Wg, Zgb);
    alpha_k<<<NODES, NHEADS * 64, 0, stream>>>(rowptr, csr_src, el, er, aw);
    gat_agg<<<NODES, 256, 0, stream>>>(rowptr, csr_src, aw, Zgb, bg, H);

    // ---- GraphConv 3: 128 -> 1, sigmoid ----
    rowdot<<<(NODES * 64 + 255) / 256, 256, 0, stream>>>(H, inv_o, W3, s1);
    gc3_gather<<<(NODES + 255) / 256, 256, 0, stream>>>(rowptr, csr_src, s1, inv_i, b3, (float*)d_out);
}

// Round 5
// 266.232 us; speedup vs baseline: 3.9761x; 1.0733x over previous
//
#include <hip/hip_runtime.h>
#include <hip/hip_bf16.h>

#define NODES   10000
#define EDGES   320000
#define INF_    256
#define HIDF    128
#define NHEADS  4
#define SCAN_T  1024
#define SCAN_C  10

typedef __attribute__((ext_vector_type(8))) short short8v;   // 8 bf16
typedef __attribute__((ext_vector_type(4))) float f32x4;

__device__ __forceinline__ float bf_lo(unsigned z) { return __uint_as_float(z << 16); }
__device__ __forceinline__ float bf_hi(unsigned z) { return __uint_as_float(z & 0xffff0000u); }
__device__ __forceinline__ unsigned short bfr(float x) {
    __hip_bfloat16 b = __float2bfloat16(x);
    return *(unsigned short*)&b;
}

// ---------------- degree ----------------
__global__ void deg_kernel(const int* __restrict__ src, const int* __restrict__ dst,
                           int* __restrict__ deg_o, int* __restrict__ deg_i) {
    int e = blockIdx.x * blockDim.x + threadIdx.x;
    if (e < EDGES) {
        atomicAdd(&deg_o[src[e]], 1);
        atomicAdd(&deg_i[dst[e]], 1);
    }
}

// ---------------- scan of deg_i -> rowptr/cursor, plus inv norms ----------------
__global__ void scan_inv(const int* __restrict__ deg_i, const int* __restrict__ deg_o,
                         int* __restrict__ rowptr, int* __restrict__ cursor,
                         float* __restrict__ inv_o, float* __restrict__ inv_i) {
    __shared__ int part[SCAN_T];
    int t = threadIdx.x;
    int base = t * SCAN_C;
    int local[SCAN_C];
    int s = 0;
    for (int j = 0; j < SCAN_C; ++j) {
        int idx = base + j;
        int v = idx < NODES ? deg_i[idx] : 0;
        local[j] = s;
        s += v;
    }
    part[t] = s;
    __syncthreads();
    for (int off = 1; off < SCAN_T; off <<= 1) {
        int v = (t >= off) ? part[t - off] : 0;
        __syncthreads();
        part[t] += v;
        __syncthreads();
    }
    int offs = (t > 0) ? part[t - 1] : 0;
    for (int j = 0; j < SCAN_C; ++j) {
        int idx = base + j;
        if (idx < NODES) {
            int r = offs + local[j];
            rowptr[idx] = r;
            cursor[idx] = r;
            inv_i[idx] = rsqrtf(fmaxf((float)deg_i[idx], 1.0f));
            inv_o[idx] = rsqrtf(fmaxf((float)deg_o[idx], 1.0f));
        }
    }
    if (t == SCAN_T - 1) rowptr[NODES] = part[SCAN_T - 1];
}

__global__ void csr_fill(const int* __restrict__ src, const int* __restrict__ dst,
                         int* __restrict__ cursor, int* __restrict__ csr_src) {
    int e = blockIdx.x * blockDim.x + threadIdx.x;
    if (e < EDGES) {
        int pos = atomicAdd(&cursor[dst[e]], 1);
        csr_src[pos] = src[e];
    }
}

// ---------------- weight prep: bf16 transposed copies [N][K] ----------------
__global__ void wprep(const float* __restrict__ W1, const float* __restrict__ W2,
                      const float* __restrict__ Wg, unsigned short* __restrict__ W1t,
                      unsigned short* __restrict__ W2t, unsigned short* __restrict__ Wgt) {
    int id = blockIdx.x * 256 + threadIdx.x;
    if (id < 128 * 256) {                 // W1 [256][128] -> W1t [128][256]
        int n = id >> 8, k = id & 255;
        W1t[id] = bfr(W1[k * HIDF + n]);
        return;
    }
    id -= 128 * 256;
    if (id < 128 * 128) {                 // W2 [128][128] -> W2t [128][128]
        int n = id >> 7, k = id & 127;
        W2t[id] = bfr(W2[k * HIDF + n]);
        return;
    }
    id -= 128 * 128;
    if (id < 512 * 128) {                 // Wg [128][512] -> Wgt [512][128]
        int n = id >> 7, k = id & 127;
        Wgt[id] = bfr(Wg[k * 512 + n]);
    }
}

// ---------------- fold attn vectors through Wg; cdot = 0.25*(sum_h bg_h)·W3 ----------------
__global__ void attn_w_k(const float* __restrict__ Wg, const float* __restrict__ attn_l,
                         const float* __restrict__ attn_r, const float* __restrict__ bg,
                         const float* __restrict__ W3, float* __restrict__ WL,
                         float* __restrict__ WR, float* __restrict__ cdot) {
    __shared__ float red[HIDF];
    int id = threadIdx.x;  // 512
    int k = id >> 2, h = id & 3;
    float a = 0.f, b = 0.f;
    for (int d = 0; d < HIDF; ++d) {
        float w = Wg[k * 512 + h * HIDF + d];
        a = fmaf(w, attn_l[h * HIDF + d], a);
        b = fmaf(w, attn_r[h * HIDF + d], b);
    }
    WL[id] = a;
    WR[id] = b;
    if (id < HIDF) red[id] = (bg[id] + bg[id + 128] + bg[id + 256] + bg[id + 384]) * W3[id];
    __syncthreads();
    if (id == 0) {
        float s = 0.f;
        for (int t = 0; t < HIDF; ++t) s += red[t];
        cdot[0] = 0.25f * s;
    }
}

// ---------------- feat -> bf16, scaled by inv_o ----------------
__global__ void feat_cvt(const float* __restrict__ feat, const float* __restrict__ inv_o,
                         unsigned short* __restrict__ Ab) {
    int id = blockIdx.x * 256 + threadIdx.x;   // NODES*64 float4's
    if (id >= NODES * (INF_ / 4)) return;
    int n = id / (INF_ / 4);
    float4 v = ((const float4*)feat)[id];
    float s = inv_o[n];
    unsigned p0 = ((unsigned)bfr(v.y * s) << 16) | bfr(v.x * s);
    unsigned p1 = ((unsigned)bfr(v.w * s) << 16) | bfr(v.z * s);
    uint2 o; o.x = p0; o.y = p1;
    ((uint2*)Ab)[id] = o;
}

// ---------------- MFMA GEMM: Y = A[M,K] @ Bt[N,K]^T, bf16 ----------------
// a_frag: A[m = lane&15][k = (lane>>4)*8 + j]; b_frag: B[k][n = lane&15]
// D[m = (lane>>4)*4 + r][n = lane&15]
template<int K, int HEADMAJ>
__global__ __launch_bounds__(256)
void mfma_gemm(const unsigned short* __restrict__ A, const unsigned short* __restrict__ Bt,
               unsigned short* __restrict__ Y, int NTOT) {
    int w = threadIdx.x >> 6, l = threadIdx.x & 63;
    int m0 = blockIdx.x * 16;
    int n0 = blockIdx.y * 64 + w * 16;
    int lm = l & 15, lk = (l >> 4) * 8;
    const short8v* Ap = (const short8v*)(A + (size_t)(m0 + lm) * K + lk);
    const short8v* Bp = (const short8v*)(Bt + (size_t)(n0 + lm) * K + lk);
    f32x4 acc = {0.f, 0.f, 0.f, 0.f};
#pragma unroll
    for (int kk = 0; kk < K / 32; ++kk) {
        short8v a = Ap[kk * 4];
        short8v b = Bp[kk * 4];
        acc = __builtin_amdgcn_mfma_f32_16x16x32_bf16(a, b, acc, 0, 0, 0);
    }
    int rbase = m0 + (l >> 4) * 4;
    int c = n0 + lm;
#pragma unroll
    for (int r = 0; r < 4; ++r) {
        int row = rbase + r;
        size_t off = HEADMAJ ? ((size_t)(c >> 7) * NODES + row) * HIDF + (c & 127)
                             : (size_t)row * NTOT + c;
        Y[off] = bfr(acc[r]);
    }
}

// ---------------- GraphConv gather: 1 wave/node, 2 edges in flight, bf16x4 loads ----------
// MODE 1: out = bf16(relu(agg*inv_i + b) * inv_o)          (feeds next GEMM)
// MODE 2: out = bf16(relu(agg*inv_i + b)); also el/er via WL/WR  (feeds GAT)
template<int MODE>
__global__ __launch_bounds__(64)
void gc_gather(const int* __restrict__ rowptr, const int* __restrict__ csr_src,
               const unsigned short* __restrict__ Zb, const float* __restrict__ inv_i,
               const float* __restrict__ inv_o, const float* __restrict__ bias,
               unsigned short* __restrict__ Hb, const float* __restrict__ WL,
               const float* __restrict__ WR, float* __restrict__ el, float* __restrict__ er) {
    int n = blockIdx.x;
    int l = threadIdx.x;
    int half = l >> 5, q = l & 31;      // lanes 0-31: even slots, 32-63: odd slots
    int beg = rowptr[n], end = rowptr[n + 1];
    float a0 = 0.f, a1 = 0.f, a2 = 0.f, a3 = 0.f;
#pragma unroll 2
    for (int i = beg + half; i < end; i += 2) {
        int s = csr_src[i];
        uint2 z = *(const uint2*)&Zb[s * HIDF + 4 * q];
        a0 += bf_lo(z.x); a1 += bf_hi(z.x);
        a2 += bf_lo(z.y); a3 += bf_hi(z.y);
    }
    a0 += __shfl_xor(a0, 32, 64);
    a1 += __shfl_xor(a1, 32, 64);
    a2 += __shfl_xor(a2, 32, 64);
    a3 += __shfl_xor(a3, 32, 64);
    float sc = inv_i[n];
    float v0 = fmaxf(a0 * sc + bias[4 * q + 0], 0.f);
    float v1 = fmaxf(a1 * sc + bias[4 * q + 1], 0.f);
    float v2 = fmaxf(a2 * sc + bias[4 * q + 2], 0.f);
    float v3 = fmaxf(a3 * sc + bias[4 * q + 3], 0.f);
    float w0 = v0, w1 = v1, w2 = v2, w3v = v3;
    if (MODE == 1) {
        float so = inv_o[n];
        w0 *= so; w1 *= so; w2 *= so; w3v *= so;
    }
    if (l < 32) {
        uint2 o;
        o.x = ((unsigned)bfr(w1) << 16) | bfr(w0);
        o.y = ((unsigned)bfr(w3v) << 16) | bfr(w2);
        *(uint2*)&Hb[n * HIDF + 4 * q] = o;
    }
    if (MODE == 2) {
        float elh[NHEADS] = {0.f, 0.f, 0.f, 0.f};
        float erh[NHEADS] = {0.f, 0.f, 0.f, 0.f};
        if (l < 32) {
            float vv[4] = {v0, v1, v2, v3};
#pragma unroll
            for (int j = 0; j < 4; ++j) {
                int k = 4 * q + j;
#pragma unroll
                for (int h = 0; h < NHEADS; ++h) {
                    elh[h] = fmaf(vv[j], WL[k * NHEADS + h], elh[h]);
                    erh[h] = fmaf(vv[j], WR[k * NHEADS + h], erh[h]);
                }
            }
        }
#pragma unroll
        for (int h = 0; h < NHEADS; ++h) {
#pragma unroll
            for (int off = 32; off; off >>= 1) {
                elh[h] += __shfl_xor(elh[h], off, 64);
                erh[h] += __shfl_xor(erh[h], off, 64);
            }
        }
        if (l == 0) {
#pragma unroll
            for (int h = 0; h < NHEADS; ++h) {
                el[n * NHEADS + h] = elh[h];
                er[n * NHEADS + h] = erh[h];
            }
        }
    }
}

// ---------------- fused GAT: 1 wave per (node, head), XCD-pinned head slices ------------
// logits in registers (deg <= 128), wave softmax, aggregate via lane broadcast,
// epilogue folds the head's W3 dot -> ps[n][h]. H is never materialized.
__global__ __launch_bounds__(64)
void gat_fused(const int* __restrict__ rowptr, const int* __restrict__ csr_src,
               const float* __restrict__ el, const float* __restrict__ er,
               const unsigned short* __restrict__ Zg /*[4][NODES][128]*/,
               const float* __restrict__ w3, float* __restrict__ ps) {
    int x = blockIdx.x;
    int h = (x & 7) >> 1;                    // heads pinned to XCD pairs (x%8 assumed XCD)
    int n = ((x >> 3) << 1) | (x & 1);
    int l = threadIdx.x;
    int beg = rowptr[n], end = rowptr[n + 1];
    int deg = end - beg;
    float ern = er[n * NHEADS + h];
    int i0 = beg + l, i1 = beg + 64 + l;
    int s0 = 0, s1 = 0;
    float lg0 = -1e30f, lg1 = -1e30f;
    if (i0 < end) {
        s0 = csr_src[i0];
        float t = el[s0 * NHEADS + h] + ern;
        lg0 = t > 0.f ? t : 0.2f * t;
    }
    if (i1 < end) {
        s1 = csr_src[i1];
        float t = el[s1 * NHEADS + h] + ern;
        lg1 = t > 0.f ? t : 0.2f * t;
    }
    float m = fmaxf(lg0, lg1);
#pragma unroll
    for (int off = 32; off; off >>= 1) m = fmaxf(m, __shfl_xor(m, off, 64));
    float ex0 = (i0 < end) ? __expf(lg0 - m) : 0.f;
    float ex1 = (i1 < end) ? __expf(lg1 - m) : 0.f;
    float den = ex0 + ex1;
#pragma unroll
    for (int off = 32; off; off >>= 1) den += __shfl_xor(den, off, 64);
    const unsigned short* Zh = Zg + (size_t)h * NODES * HIDF;
    float a0 = 0.f, a1 = 0.f;
    for (int ii = 0; ii < deg; ++ii) {
        int sv   = (ii < 64) ? __shfl(s0, ii, 64) : __shfl(s1, ii - 64, 64);
        float ev = (ii < 64) ? __shfl(ex0, ii, 64) : __shfl(ex1, ii - 64, 64);
        unsigned z = *(const unsigned*)&Zh[sv * HIDF + 2 * l];
        a0 = fmaf(ev, bf_lo(z), a0);
        a1 = fmaf(ev, bf_hi(z), a1);
    }
    float pd = a0 * w3[2 * l] + a1 * w3[2 * l + 1];
#pragma unroll
    for (int off = 32; off; off >>= 1) pd += __shfl_xor(pd, off, 64);
    if (l == 0) ps[n * NHEADS + h] = den > 0.f ? pd / den : 0.f;
}

// ---------------- s1[n] = inv_o[n]*(0.25*sum_h ps + cdot) ----------------
__global__ void s1_k(const float* __restrict__ ps, const float* __restrict__ inv_o,
                     const float* __restrict__ cdot, float* __restrict__ s1v) {
    int n = blockIdx.x * blockDim.x + threadIdx.x;
    if (n < NODES) {
        float v = ps[n * 4] + ps[n * 4 + 1] + ps[n * 4 + 2] + ps[n * 4 + 3];
        s1v[n] = inv_o[n] * (0.25f * v + cdot[0]);
    }
}

// ---------------- GC3 gather + sigmoid ----------------
__global__ void gc3_gather(const int* __restrict__ rowptr, const int* __restrict__ csr_src,
                           const float* __restrict__ s1v, const float* __restrict__ inv_i,
                           const float* __restrict__ b3, float* __restrict__ out) {
    int n = blockIdx.x * blockDim.x + threadIdx.x;
    if (n >= NODES) return;
    int beg = rowptr[n], end = rowptr[n + 1];
    float acc = 0.f;
    for (int i = beg; i < end; ++i) acc += s1v[csr_src[i]];
    float x = acc * inv_i[n] + b3[0];
    out[n] = 1.f / (1.f + __expf(-x));
}

extern "C" void kernel_launch(void* const* d_in, const int* in_sizes, int n_in,
                              void* d_out, int out_size, void* d_ws, size_t ws_size,
                              hipStream_t stream) {
    const float* feat   = (const float*)d_in[0];
    const int*   src    = (const int*)d_in[1];
    const int*   dst    = (const int*)d_in[2];
    const float* W1     = (const float*)d_in[3];
    const float* b1     = (const float*)d_in[4];
    const float* W2     = (const float*)d_in[5];
    const float* b2     = (const float*)d_in[6];
    const float* W3     = (const float*)d_in[7];
    const float* b3     = (const float*)d_in[8];
    const float* Wg     = (const float*)d_in[9];
    const float* attn_l = (const float*)d_in[10];
    const float* attn_r = (const float*)d_in[11];
    const float* bg     = (const float*)d_in[12];

    char* w = (char*)d_ws;
    auto alloc = [&](size_t bytes) { void* p = (void*)w; w += (bytes + 255) & ~(size_t)255; return p; };
    int*   deg_o   = (int*)  alloc(NODES * 4);
    int*   deg_i   = (int*)  alloc(NODES * 4);
    float* inv_o   = (float*)alloc(NODES * 4);
    float* inv_i   = (float*)alloc(NODES * 4);
    int*   rowptr  = (int*)  alloc((NODES + 1) * 4);
    int*   cursor  = (int*)  alloc(NODES * 4);
    int*   csr_src = (int*)  alloc((size_t)EDGES * 4);
    unsigned short* W1t = (unsigned short*)alloc(128 * 256 * 2);
    unsigned short* W2t = (unsigned short*)alloc(128 * 128 * 2);
    unsigned short* Wgt = (unsigned short*)alloc(512 * 128 * 2);
    float* WL      = (float*)alloc(HIDF * NHEADS * 4);
    float* WR      = (float*)alloc(HIDF * NHEADS * 4);
    float* cdot    = (float*)alloc(256);
    float* el      = (float*)alloc(NODES * NHEADS * 4);
    float* er      = (float*)alloc(NODES * NHEADS * 4);
    float* ps      = (float*)alloc(NODES * NHEADS * 4);
    float* s1v     = (float*)alloc(NODES * 4);
    unsigned short* Abf = (unsigned short*)alloc((size_t)NODES * INF_ * 2);
    unsigned short* Zb  = (unsigned short*)alloc((size_t)NODES * HIDF * 2);
    unsigned short* H1b = (unsigned short*)alloc((size_t)NODES * HIDF * 2);
    unsigned short* H2b = (unsigned short*)alloc((size_t)NODES * HIDF * 2);
    unsigned short* Zg  = (unsigned short*)alloc((size_t)NHEADS * NODES * HIDF * 2);

    // ---- prep: weights (no graph dep), graph, feat ----
    wprep<<<448, 256, 0, stream>>>(W1, W2, Wg, W1t, W2t, Wgt);
    attn_w_k<<<1, 512, 0, stream>>>(Wg, attn_l, attn_r, bg, W3, WL, WR, cdot);
    hipMemsetAsync(deg_o, 0, NODES * 4, stream);
    hipMemsetAsync(deg_i, 0, NODES * 4, stream);
    deg_kernel<<<(EDGES + 255) / 256, 256, 0, stream>>>(src, dst, deg_o, deg_i);
    scan_inv<<<1, SCAN_T, 0, stream>>>(deg_i, deg_o, rowptr, cursor, inv_o, inv_i);
    csr_fill<<<(EDGES + 255) / 256, 256, 0, stream>>>(src, dst, cursor, csr_src);
    feat_cvt<<<(NODES * (INF_ / 4) + 255) / 256, 256, 0, stream>>>(feat, inv_o, Abf);

    // ---- GraphConv 1: (feat*inv_o)@W1 -> gather -> H1b (bf16, *inv_o folded) ----
    mfma_gemm<INF_, 0><<<dim3(NODES / 16, 2), 256, 0, stream>>>(Abf, W1t, Zb, HIDF);
    gc_gather<1><<<NODES, 64, 0, stream>>>(rowptr, csr_src, Zb, inv_i, inv_o, b1,
                                           H1b, nullptr, nullptr, nullptr, nullptr);

    // ---- GraphConv 2: H1b@W2 -> gather -> H2b (bf16) + el/er ----
    mfma_gemm<HIDF, 0><<<dim3(NODES / 16, 2), 256, 0, stream>>>(H1b, W2t, Zb, HIDF);
    gc_gather<2><<<NODES, 64, 0, stream>>>(rowptr, csr_src, Zb, inv_i, inv_o, b2,
                                           H2b, WL, WR, el, er);

    // ---- GAT: Zg = H2b@Wg (head-major), fused softmax+agg+W3-dot ----
    mfma_gemm<HIDF, 1><<<dim3(NODES / 16, 8), 256, 0, stream>>>(H2b, Wgt, Zg, NHEADS * HIDF);
    gat_fused<<<NODES * NHEADS, 64, 0, stream>>>(rowptr, csr_src, el, er, Zg, W3, ps);

    // ---- GC3: combine + gather + sigmoid ----
    s1_k<<<(NODES + 255) / 256, 256, 0, stream>>>(ps, inv_o, cdot, s1v);
    gc3_gather<<<(NODES + 255) / 256, 256, 0, stream>>>(rowptr, csr_src, s1v, inv_i, b3,
                                                        (float*)d_out);
}

// Round 6
// 223.253 us; speedup vs baseline: 4.7416x; 1.1925x over previous
//
#include <hip/hip_runtime.h>
#include <hip/hip_bf16.h>

#define NODES   10000
#define EDGES   320000
#define INF_    256
#define HIDF    128
#define NHEADS  4
#define SCAN_T  1024
#define SCAN_C  10
#define EDGE_BLKS  ((EDGES + 255) / 256)          // 1250
#define FEAT_ITEMS (NODES * (INF_ / 4))           // 640000 float4's
#define FEAT_BLKS  ((FEAT_ITEMS + 255) / 256)     // 2500
#define WPREP_ITEMS (128 * 256 + 128 * 128 + 512 * 128)  // 114688
#define WPREP_BLKS  (WPREP_ITEMS / 512)                  // 224

typedef __attribute__((ext_vector_type(8))) short short8v;   // 8 bf16
typedef __attribute__((ext_vector_type(4))) float f32x4;

__device__ __forceinline__ float bf_lo(unsigned z) { return __uint_as_float(z << 16); }
__device__ __forceinline__ float bf_hi(unsigned z) { return __uint_as_float(z & 0xffff0000u); }
__device__ __forceinline__ unsigned short bfr(float x) {
    __hip_bfloat16 b = __float2bfloat16(x);
    return *(unsigned short*)&b;
}

// ---------------- degree ----------------
__global__ void deg_kernel(const int* __restrict__ src, const int* __restrict__ dst,
                           int* __restrict__ deg_o, int* __restrict__ deg_i) {
    int e = blockIdx.x * blockDim.x + threadIdx.x;
    if (e < EDGES) {
        atomicAdd(&deg_o[src[e]], 1);
        atomicAdd(&deg_i[dst[e]], 1);
    }
}

// ---------------- scan of deg_i -> rowptr/cursor, plus inv norms ----------------
__global__ void scan_inv(const int* __restrict__ deg_i, const int* __restrict__ deg_o,
                         int* __restrict__ rowptr, int* __restrict__ cursor,
                         float* __restrict__ inv_o, float* __restrict__ inv_i) {
    __shared__ int part[SCAN_T];
    int t = threadIdx.x;
    int base = t * SCAN_C;
    int local[SCAN_C];
    int s = 0;
    for (int j = 0; j < SCAN_C; ++j) {
        int idx = base + j;
        int v = idx < NODES ? deg_i[idx] : 0;
        local[j] = s;
        s += v;
    }
    part[t] = s;
    __syncthreads();
    for (int off = 1; off < SCAN_T; off <<= 1) {
        int v = (t >= off) ? part[t - off] : 0;
        __syncthreads();
        part[t] += v;
        __syncthreads();
    }
    int offs = (t > 0) ? part[t - 1] : 0;
    for (int j = 0; j < SCAN_C; ++j) {
        int idx = base + j;
        if (idx < NODES) {
            int r = offs + local[j];
            rowptr[idx] = r;
            cursor[idx] = r;
            inv_i[idx] = rsqrtf(fmaxf((float)deg_i[idx], 1.0f));
            inv_o[idx] = rsqrtf(fmaxf((float)deg_o[idx], 1.0f));
        }
    }
    if (t == SCAN_T - 1) rowptr[NODES] = part[SCAN_T - 1];
}

// ---------------- prep0: bf16 transposed weights + folded attn vectors + cdot --------
__global__ __launch_bounds__(512)
void prep0(const float* __restrict__ W1, const float* __restrict__ W2,
           const float* __restrict__ Wg, const float* __restrict__ attn_l,
           const float* __restrict__ attn_r, const float* __restrict__ bg,
           const float* __restrict__ W3, unsigned short* __restrict__ W1t,
           unsigned short* __restrict__ W2t, unsigned short* __restrict__ Wgt,
           float* __restrict__ WL, float* __restrict__ WR, float* __restrict__ cdot) {
    int b = blockIdx.x;
    if (b < WPREP_BLKS) {
        int id = b * 512 + threadIdx.x;
        if (id < 128 * 256) {                 // W1 [256][128] -> W1t [128][256]
            int nn = id >> 8, k = id & 255;
            W1t[id] = bfr(W1[k * HIDF + nn]);
            return;
        }
        id -= 128 * 256;
        if (id < 128 * 128) {                 // W2 [128][128] -> W2t [128][128]
            int nn = id >> 7, k = id & 127;
            W2t[id] = bfr(W2[k * HIDF + nn]);
            return;
        }
        id -= 128 * 128;
        {                                     // Wg [128][512] -> Wgt [512][128]
            int nn = id >> 7, k = id & 127;
            Wgt[id] = bfr(Wg[k * 512 + nn]);
        }
        return;
    }
    // attention fold block
    __shared__ float red[HIDF];
    int id = threadIdx.x;  // 512
    int k = id >> 2, h = id & 3;
    float a = 0.f, bb = 0.f;
    for (int d = 0; d < HIDF; ++d) {
        float w = Wg[k * 512 + h * HIDF + d];
        a = fmaf(w, attn_l[h * HIDF + d], a);
        bb = fmaf(w, attn_r[h * HIDF + d], bb);
    }
    WL[id] = a;
    WR[id] = bb;
    if (id < HIDF) red[id] = (bg[id] + bg[id + 128] + bg[id + 256] + bg[id + 384]) * W3[id];
    __syncthreads();
    if (id == 0) {
        float s = 0.f;
        for (int t = 0; t < HIDF; ++t) s += red[t];
        cdot[0] = 0.25f * s;
    }
}

// ---------------- post_scan: csr_fill + feat->bf16*inv_o ----------------
__global__ void post_scan(const int* __restrict__ src, const int* __restrict__ dst,
                          int* __restrict__ cursor, int* __restrict__ csr_src,
                          const float* __restrict__ feat, const float* __restrict__ inv_o,
                          unsigned short* __restrict__ Abf) {
    int b = blockIdx.x;
    if (b < EDGE_BLKS) {
        int e = b * 256 + threadIdx.x;
        if (e < EDGES) {
            int pos = atomicAdd(&cursor[dst[e]], 1);
            csr_src[pos] = src[e];
        }
    } else {
        int id = (b - EDGE_BLKS) * 256 + threadIdx.x;
        if (id < FEAT_ITEMS) {
            int n = id >> 6;                  // /(INF_/4)
            float4 v = ((const float4*)feat)[id];
            float s = inv_o[n];
            uint2 o;
            o.x = ((unsigned)bfr(v.y * s) << 16) | bfr(v.x * s);
            o.y = ((unsigned)bfr(v.w * s) << 16) | bfr(v.z * s);
            ((uint2*)Abf)[id] = o;
        }
    }
}

// ---------------- MFMA GEMM: Y = A[M,K] @ Bt[N,K]^T, bf16; 64x64 block, 4 acc/wave ----
// a_frag: A[m=lane&15][k=(lane>>4)*8+j]; D[m=(lane>>4)*4+r][n=lane&15]
template<int K, int HEADMAJ>
__global__ __launch_bounds__(256)
void mfma_gemm(const unsigned short* __restrict__ A, const unsigned short* __restrict__ Bt,
               unsigned short* __restrict__ Y, int NTOT) {
    int w = threadIdx.x >> 6, l = threadIdx.x & 63;
    int m0 = blockIdx.x * 64 + w * 16;
    int n0 = blockIdx.y * 64;
    int lm = l & 15, lk = (l >> 4) * 8;
    int arow = min(m0 + lm, NODES - 1);
    const short8v* Ap = (const short8v*)(A + (size_t)arow * K + lk);
    const short8v* Bp = (const short8v*)(Bt + (size_t)(n0 + lm) * K + lk);
    f32x4 acc0 = {0.f, 0.f, 0.f, 0.f}, acc1 = acc0, acc2 = acc0, acc3 = acc0;
    const int BS = 2 * K;   // 16 rows * K/8 short8v's
#pragma unroll
    for (int kk = 0; kk < K / 32; ++kk) {
        short8v a = Ap[kk * 4];
        acc0 = __builtin_amdgcn_mfma_f32_16x16x32_bf16(a, Bp[kk * 4], acc0, 0, 0, 0);
        acc1 = __builtin_amdgcn_mfma_f32_16x16x32_bf16(a, Bp[kk * 4 + BS], acc1, 0, 0, 0);
        acc2 = __builtin_amdgcn_mfma_f32_16x16x32_bf16(a, Bp[kk * 4 + 2 * BS], acc2, 0, 0, 0);
        acc3 = __builtin_amdgcn_mfma_f32_16x16x32_bf16(a, Bp[kk * 4 + 3 * BS], acc3, 0, 0, 0);
    }
    int rb = m0 + (l >> 4) * 4;
    int cb = n0 + lm;
    f32x4 accs[4] = {acc0, acc1, acc2, acc3};
#pragma unroll
    for (int j = 0; j < 4; ++j) {
        int c = cb + 16 * j;
#pragma unroll
        for (int r = 0; r < 4; ++r) {
            int row = rb + r;
            if (row < NODES) {
                size_t off = HEADMAJ ? ((size_t)(c >> 7) * NODES + row) * HIDF + (c & 127)
                                     : (size_t)row * NTOT + c;
                Y[off] = bfr(accs[j][r]);
            }
        }
    }
}

// ---------------- GraphConv gather: 1 wave/node, 4 edges in flight, 16B loads ---------
// lane = quarter*16 + q; quarter handles edges i%4==quarter; q owns cols 8q..8q+7
// MODE 1: out = bf16(relu(agg*inv_i + b) * inv_o); MODE 2: + el/er via WL/WR
template<int MODE>
__global__ __launch_bounds__(64)
void gc_gather(const int* __restrict__ rowptr, const int* __restrict__ csr_src,
               const unsigned short* __restrict__ Zb, const float* __restrict__ inv_i,
               const float* __restrict__ inv_o, const float* __restrict__ bias,
               unsigned short* __restrict__ Hb, const float* __restrict__ WL,
               const float* __restrict__ WR, float* __restrict__ el, float* __restrict__ er) {
    int n = blockIdx.x;
    int l = threadIdx.x;
    int quarter = l >> 4, q = l & 15;
    int beg = rowptr[n], end = rowptr[n + 1];
    float a[8] = {0.f, 0.f, 0.f, 0.f, 0.f, 0.f, 0.f, 0.f};
    for (int i = beg + quarter; i < end; i += 4) {
        int s = csr_src[i];
        uint4 z = *(const uint4*)&Zb[s * HIDF + 8 * q];
        a[0] += bf_lo(z.x); a[1] += bf_hi(z.x);
        a[2] += bf_lo(z.y); a[3] += bf_hi(z.y);
        a[4] += bf_lo(z.z); a[5] += bf_hi(z.z);
        a[6] += bf_lo(z.w); a[7] += bf_hi(z.w);
    }
#pragma unroll
    for (int j = 0; j < 8; ++j) {
        a[j] += __shfl_xor(a[j], 16, 64);
        a[j] += __shfl_xor(a[j], 32, 64);
    }
    float sc = inv_i[n];
    float v[8];
#pragma unroll
    for (int j = 0; j < 8; ++j) v[j] = fmaxf(fmaf(a[j], sc, bias[8 * q + j]), 0.f);
    if (l < 16) {
        float so = (MODE == 1) ? inv_o[n] : 1.f;
        uint4 o;
        o.x = ((unsigned)bfr(v[1] * so) << 16) | bfr(v[0] * so);
        o.y = ((unsigned)bfr(v[3] * so) << 16) | bfr(v[2] * so);
        o.z = ((unsigned)bfr(v[5] * so) << 16) | bfr(v[4] * so);
        o.w = ((unsigned)bfr(v[7] * so) << 16) | bfr(v[6] * so);
        *(uint4*)&Hb[n * HIDF + 8 * q] = o;
    }
    if (MODE == 2) {
        float elh[NHEADS] = {0.f, 0.f, 0.f, 0.f};
        float erh[NHEADS] = {0.f, 0.f, 0.f, 0.f};
#pragma unroll
        for (int j = 0; j < 8; ++j) {
            int k = 8 * q + j;
#pragma unroll
            for (int h = 0; h < NHEADS; ++h) {
                elh[h] = fmaf(v[j], WL[k * NHEADS + h], elh[h]);
                erh[h] = fmaf(v[j], WR[k * NHEADS + h], erh[h]);
            }
        }
        // reduce over q only (quarters hold duplicates): offsets 1..8
#pragma unroll
        for (int h = 0; h < NHEADS; ++h) {
#pragma unroll
            for (int off = 1; off <= 8; off <<= 1) {
                elh[h] += __shfl_xor(elh[h], off, 64);
                erh[h] += __shfl_xor(erh[h], off, 64);
            }
        }
        if (l == 0) {
#pragma unroll
            for (int h = 0; h < NHEADS; ++h) {
                el[n * NHEADS + h] = elh[h];
                er[n * NHEADS + h] = erh[h];
            }
        }
    }
}

// ---------------- fused GAT: 1 wave/(node,head); LDS (src,ex) pairs; 4 edges in flight
__global__ __launch_bounds__(64)
void gat_fused(const int* __restrict__ rowptr, const int* __restrict__ csr_src,
               const float* __restrict__ el, const float* __restrict__ er,
               const unsigned short* __restrict__ Zg /*[4][NODES][128]*/,
               const float* __restrict__ w3, float* __restrict__ ps) {
    __shared__ int2 se[128];
    int x = blockIdx.x;
    int h = (x & 7) >> 1;                    // heads pinned to XCD pairs
    int n = ((x >> 3) << 1) | (x & 1);
    int l = threadIdx.x;
    int beg = rowptr[n], end = rowptr[n + 1];
    int deg = end - beg;
    float ern = er[n * NHEADS + h];
    int i0 = beg + l, i1 = beg + 64 + l;
    int s0 = 0, s1 = 0;
    float lg0 = -1e30f, lg1 = -1e30f;
    if (i0 < end) {
        s0 = csr_src[i0];
        float t = el[s0 * NHEADS + h] + ern;
        lg0 = t > 0.f ? t : 0.2f * t;
    }
    if (i1 < end) {
        s1 = csr_src[i1];
        float t = el[s1 * NHEADS + h] + ern;
        lg1 = t > 0.f ? t : 0.2f * t;
    }
    float m = fmaxf(lg0, lg1);
#pragma unroll
    for (int off = 32; off; off >>= 1) m = fmaxf(m, __shfl_xor(m, off, 64));
    float ex0 = (i0 < end) ? __expf(lg0 - m) : 0.f;
    float ex1 = (i1 < end) ? __expf(lg1 - m) : 0.f;
    float den = ex0 + ex1;
#pragma unroll
    for (int off = 32; off; off >>= 1) den += __shfl_xor(den, off, 64);
    se[l] = make_int2(s0, __float_as_int(ex0));
    se[64 + l] = make_int2(s1, __float_as_int(ex1));
    __syncthreads();
    int quarter = l >> 4, q = l & 15;
    const unsigned short* Zh = Zg + (size_t)h * NODES * HIDF;
    float a[8] = {0.f, 0.f, 0.f, 0.f, 0.f, 0.f, 0.f, 0.f};
    for (int ii = quarter; ii < deg; ii += 4) {
        int2 p = se[ii];
        float ev = __int_as_float(p.y);
        uint4 z = *(const uint4*)&Zh[(size_t)p.x * HIDF + 8 * q];
        a[0] = fmaf(ev, bf_lo(z.x), a[0]); a[1] = fmaf(ev, bf_hi(z.x), a[1]);
        a[2] = fmaf(ev, bf_lo(z.y), a[2]); a[3] = fmaf(ev, bf_hi(z.y), a[3]);
        a[4] = fmaf(ev, bf_lo(z.z), a[4]); a[5] = fmaf(ev, bf_hi(z.z), a[5]);
        a[6] = fmaf(ev, bf_lo(z.w), a[6]); a[7] = fmaf(ev, bf_hi(z.w), a[7]);
    }
#pragma unroll
    for (int j = 0; j < 8; ++j) {
        a[j] += __shfl_xor(a[j], 16, 64);
        a[j] += __shfl_xor(a[j], 32, 64);
    }
    float pd = 0.f;
#pragma unroll
    for (int j = 0; j < 8; ++j) pd = fmaf(a[j], w3[8 * q + j], pd);
#pragma unroll
    for (int off = 1; off <= 8; off <<= 1) pd += __shfl_xor(pd, off, 64);
    if (l == 0) ps[n * NHEADS + h] = den > 0.f ? pd / den : 0.f;
}

// ---------------- s1[n] = inv_o[n]*(0.25*sum_h ps + cdot) ----------------
__global__ void s1_k(const float* __restrict__ ps, const float* __restrict__ inv_o,
                     const float* __restrict__ cdot, float* __restrict__ s1v) {
    int n = blockIdx.x * blockDim.x + threadIdx.x;
    if (n < NODES) {
        float v = ps[n * 4] + ps[n * 4 + 1] + ps[n * 4 + 2] + ps[n * 4 + 3];
        s1v[n] = inv_o[n] * (0.25f * v + cdot[0]);
    }
}

// ---------------- GC3 gather + sigmoid: 1 wave/node ----------------
__global__ __launch_bounds__(64)
void gc3_gather(const int* __restrict__ rowptr, const int* __restrict__ csr_src,
                const float* __restrict__ s1v, const float* __restrict__ inv_i,
                const float* __restrict__ b3, float* __restrict__ out) {
    int n = blockIdx.x;
    int l = threadIdx.x;
    int beg = rowptr[n], end = rowptr[n + 1];
    float acc = 0.f;
    for (int i = beg + l; i < end; i += 64) acc += s1v[csr_src[i]];
#pragma unroll
    for (int off = 32; off; off >>= 1) acc += __shfl_xor(acc, off, 64);
    if (l == 0) {
        float xv = acc * inv_i[n] + b3[0];
        out[n] = 1.f / (1.f + __expf(-xv));
    }
}

extern "C" void kernel_launch(void* const* d_in, const int* in_sizes, int n_in,
                              void* d_out, int out_size, void* d_ws, size_t ws_size,
                              hipStream_t stream) {
    const float* feat   = (const float*)d_in[0];
    const int*   src    = (const int*)d_in[1];
    const int*   dst    = (const int*)d_in[2];
    const float* W1     = (const float*)d_in[3];
    const float* b1     = (const float*)d_in[4];
    const float* W2     = (const float*)d_in[5];
    const float* b2     = (const float*)d_in[6];
    const float* W3     = (const float*)d_in[7];
    const float* b3     = (const float*)d_in[8];
    const float* Wg     = (const float*)d_in[9];
    const float* attn_l = (const float*)d_in[10];
    const float* attn_r = (const float*)d_in[11];
    const float* bg     = (const float*)d_in[12];

    char* w = (char*)d_ws;
    auto alloc = [&](size_t bytes) { void* p = (void*)w; w += (bytes + 255) & ~(size_t)255; return p; };
    int*   deg     = (int*)  alloc(2 * NODES * 4);   // deg_o | deg_i contiguous
    int*   deg_o   = deg;
    int*   deg_i   = deg + NODES;
    float* inv_o   = (float*)alloc(NODES * 4);
    float* inv_i   = (float*)alloc(NODES * 4);
    int*   rowptr  = (int*)  alloc((NODES + 1) * 4);
    int*   cursor  = (int*)  alloc(NODES * 4);
    int*   csr_src = (int*)  alloc((size_t)EDGES * 4);
    unsigned short* W1t = (unsigned short*)alloc(128 * 256 * 2);
    unsigned short* W2t = (unsigned short*)alloc(128 * 128 * 2);
    unsigned short* Wgt = (unsigned short*)alloc(512 * 128 * 2);
    float* WL      = (float*)alloc(HIDF * NHEADS * 4);
    float* WR      = (float*)alloc(HIDF * NHEADS * 4);
    float* cdot    = (float*)alloc(256);
    float* el      = (float*)alloc(NODES * NHEADS * 4);
    float* er      = (float*)alloc(NODES * NHEADS * 4);
    float* ps      = (float*)alloc(NODES * NHEADS * 4);
    float* s1v     = (float*)alloc(NODES * 4);
    unsigned short* Abf = (unsigned short*)alloc((size_t)NODES * INF_ * 2);
    unsigned short* Zb  = (unsigned short*)alloc((size_t)NODES * HIDF * 2);
    unsigned short* H1b = (unsigned short*)alloc((size_t)NODES * HIDF * 2);
    unsigned short* H2b = (unsigned short*)alloc((size_t)NODES * HIDF * 2);
    unsigned short* Zg  = (unsigned short*)alloc((size_t)NHEADS * NODES * HIDF * 2);

    // ---- prep ----
    hipMemsetAsync(deg, 0, 2 * NODES * 4, stream);
    prep0<<<WPREP_BLKS + 1, 512, 0, stream>>>(W1, W2, Wg, attn_l, attn_r, bg, W3,
                                              W1t, W2t, Wgt, WL, WR, cdot);
    deg_kernel<<<EDGE_BLKS, 256, 0, stream>>>(src, dst, deg_o, deg_i);
    scan_inv<<<1, SCAN_T, 0, stream>>>(deg_i, deg_o, rowptr, cursor, inv_o, inv_i);
    post_scan<<<EDGE_BLKS + FEAT_BLKS, 256, 0, stream>>>(src, dst, cursor, csr_src,
                                                         feat, inv_o, Abf);

    // ---- GraphConv 1 ----
    mfma_gemm<INF_, 0><<<dim3((NODES + 63) / 64, 2), 256, 0, stream>>>(Abf, W1t, Zb, HIDF);
    gc_gather<1><<<NODES, 64, 0, stream>>>(rowptr, csr_src, Zb, inv_i, inv_o, b1,
                                           H1b, nullptr, nullptr, nullptr, nullptr);

    // ---- GraphConv 2 (+ el/er epilogue) ----
    mfma_gemm<HIDF, 0><<<dim3((NODES + 63) / 64, 2), 256, 0, stream>>>(H1b, W2t, Zb, HIDF);
    gc_gather<2><<<NODES, 64, 0, stream>>>(rowptr, csr_src, Zb, inv_i, inv_o, b2,
                                           H2b, WL, WR, el, er);

    // ---- GAT ----
    mfma_gemm<HIDF, 1><<<dim3((NODES + 63) / 64, 8), 256, 0, stream>>>(H2b, Wgt, Zg, NHEADS * HIDF);
    gat_fused<<<NODES * NHEADS, 64, 0, stream>>>(rowptr, csr_src, el, er, Zg, W3, ps);

    // ---- GC3 ----
    s1_k<<<(NODES + 255) / 256, 256, 0, stream>>>(ps, inv_o, cdot, s1v);
    gc3_gather<<<NODES, 64, 0, stream>>>(rowptr, csr_src, s1v, inv_i, b3, (float*)d_out);
}

// Round 7
// 217.419 us; speedup vs baseline: 4.8688x; 1.0268x over previous
//
#include <hip/hip_runtime.h>
#include <hip/hip_bf16.h>

#define NODES   10000
#define EDGES   320000
#define INF_    256
#define HIDF    128
#define NHEADS  4
#define SCAN_T  1024
#define SCAN_C  10
#define EDGE_BLKS  ((EDGES + 255) / 256)          // 1250
#define FEAT_ITEMS (NODES * (INF_ / 4))           // 640000 float4's
#define FEAT_BLKS  ((FEAT_ITEMS + 255) / 256)     // 2500
#define WPREP_ITEMS (128 * 256 + 128 * 128 + 512 * 128)  // 114688
#define WPREP_BLKS  (WPREP_ITEMS / 512)                  // 224
#define DEGZ_BLKS  ((2 * NODES + 511) / 512)             // 40

typedef __attribute__((ext_vector_type(8))) short short8v;   // 8 bf16
typedef __attribute__((ext_vector_type(4))) float f32x4;

__device__ __forceinline__ float bf_lo(unsigned z) { return __uint_as_float(z << 16); }
__device__ __forceinline__ float bf_hi(unsigned z) { return __uint_as_float(z & 0xffff0000u); }
__device__ __forceinline__ unsigned short bfr(float x) {
    __hip_bfloat16 b = __float2bfloat16(x);
    return *(unsigned short*)&b;
}

// ---------------- degree ----------------
__global__ void deg_kernel(const int* __restrict__ src, const int* __restrict__ dst,
                           int* __restrict__ deg_o, int* __restrict__ deg_i) {
    int e = blockIdx.x * blockDim.x + threadIdx.x;
    if (e < EDGES) {
        atomicAdd(&deg_o[src[e]], 1);
        atomicAdd(&deg_i[dst[e]], 1);
    }
}

// ---------------- scan of deg_i -> rowptr/cursor, plus inv norms ----------------
__global__ void scan_inv(const int* __restrict__ deg_i, const int* __restrict__ deg_o,
                         int* __restrict__ rowptr, int* __restrict__ cursor,
                         float* __restrict__ inv_o, float* __restrict__ inv_i) {
    __shared__ int part[SCAN_T];
    int t = threadIdx.x;
    int base = t * SCAN_C;
    int local[SCAN_C];
    int s = 0;
    for (int j = 0; j < SCAN_C; ++j) {
        int idx = base + j;
        int v = idx < NODES ? deg_i[idx] : 0;
        local[j] = s;
        s += v;
    }
    part[t] = s;
    __syncthreads();
    for (int off = 1; off < SCAN_T; off <<= 1) {
        int v = (t >= off) ? part[t - off] : 0;
        __syncthreads();
        part[t] += v;
        __syncthreads();
    }
    int offs = (t > 0) ? part[t - 1] : 0;
    for (int j = 0; j < SCAN_C; ++j) {
        int idx = base + j;
        if (idx < NODES) {
            int r = offs + local[j];
            rowptr[idx] = r;
            cursor[idx] = r;
            inv_i[idx] = rsqrtf(fmaxf((float)deg_i[idx], 1.0f));
            inv_o[idx] = rsqrtf(fmaxf((float)deg_o[idx], 1.0f));
        }
    }
    if (t == SCAN_T - 1) rowptr[NODES] = part[SCAN_T - 1];
}

// ---- prep0: bf16 transposed weights + folded attn vectors + cdot + zero degrees ----
__global__ __launch_bounds__(512)
void prep0(const float* __restrict__ W1, const float* __restrict__ W2,
           const float* __restrict__ Wg, const float* __restrict__ attn_l,
           const float* __restrict__ attn_r, const float* __restrict__ bg,
           const float* __restrict__ W3, unsigned short* __restrict__ W1t,
           unsigned short* __restrict__ W2t, unsigned short* __restrict__ Wgt,
           float* __restrict__ WL, float* __restrict__ WR, float* __restrict__ cdot,
           int* __restrict__ deg) {
    int b = blockIdx.x;
    if (b < WPREP_BLKS) {
        int id = b * 512 + threadIdx.x;
        if (id < 128 * 256) {                 // W1 [256][128] -> W1t [128][256]
            int nn = id >> 8, k = id & 255;
            W1t[id] = bfr(W1[k * HIDF + nn]);
            return;
        }
        id -= 128 * 256;
        if (id < 128 * 128) {                 // W2 [128][128] -> W2t [128][128]
            int nn = id >> 7, k = id & 127;
            W2t[id] = bfr(W2[k * HIDF + nn]);
            return;
        }
        id -= 128 * 128;
        {                                     // Wg [128][512] -> Wgt [512][128]
            int nn = id >> 7, k = id & 127;
            Wgt[id] = bfr(Wg[k * 512 + nn]);
        }
        return;
    }
    if (b > WPREP_BLKS) {                     // zero deg_o|deg_i (2*NODES ints)
        int id = (b - WPREP_BLKS - 1) * 512 + threadIdx.x;
        if (id < 2 * NODES) deg[id] = 0;
        return;
    }
    // attention fold block (b == WPREP_BLKS)
    __shared__ float red[HIDF];
    int id = threadIdx.x;  // 512
    int k = id >> 2, h = id & 3;
    float a = 0.f, bb = 0.f;
    for (int d = 0; d < HIDF; ++d) {
        float w = Wg[k * 512 + h * HIDF + d];
        a = fmaf(w, attn_l[h * HIDF + d], a);
        bb = fmaf(w, attn_r[h * HIDF + d], bb);
    }
    WL[id] = a;
    WR[id] = bb;
    if (id < HIDF) red[id] = (bg[id] + bg[id + 128] + bg[id + 256] + bg[id + 384]) * W3[id];
    __syncthreads();
    if (id == 0) {
        float s = 0.f;
        for (int t = 0; t < HIDF; ++t) s += red[t];
        cdot[0] = 0.25f * s;
    }
}

// ---------------- post_scan: csr_fill + feat->bf16*inv_o ----------------
__global__ void post_scan(const int* __restrict__ src, const int* __restrict__ dst,
                          int* __restrict__ cursor, int* __restrict__ csr_src,
                          const float* __restrict__ feat, const float* __restrict__ inv_o,
                          unsigned short* __restrict__ Abf) {
    int b = blockIdx.x;
    if (b < EDGE_BLKS) {
        int e = b * 256 + threadIdx.x;
        if (e < EDGES) {
            int pos = atomicAdd(&cursor[dst[e]], 1);
            csr_src[pos] = src[e];
        }
    } else {
        int id = (b - EDGE_BLKS) * 256 + threadIdx.x;
        if (id < FEAT_ITEMS) {
            int n = id >> 6;                  // /(INF_/4)
            float4 v = ((const float4*)feat)[id];
            float s = inv_o[n];
            uint2 o;
            o.x = ((unsigned)bfr(v.y * s) << 16) | bfr(v.x * s);
            o.y = ((unsigned)bfr(v.w * s) << 16) | bfr(v.z * s);
            ((uint2*)Abf)[id] = o;
        }
    }
}

// ---------------- MFMA GEMM: Y = A[M,K] @ Bt[N,K]^T, bf16; 64x64 block, 4 acc/wave ----
// a_frag: A[m=lane&15][k=(lane>>4)*8+j]; D[m=(lane>>4)*4+r][n=lane&15]
template<int K, int HEADMAJ>
__global__ __launch_bounds__(256)
void mfma_gemm(const unsigned short* __restrict__ A, const unsigned short* __restrict__ Bt,
               unsigned short* __restrict__ Y, int NTOT) {
    int w = threadIdx.x >> 6, l = threadIdx.x & 63;
    int m0 = blockIdx.x * 64 + w * 16;
    int n0 = blockIdx.y * 64;
    int lm = l & 15, lk = (l >> 4) * 8;
    int arow = min(m0 + lm, NODES - 1);
    const short8v* Ap = (const short8v*)(A + (size_t)arow * K + lk);
    const short8v* Bp = (const short8v*)(Bt + (size_t)(n0 + lm) * K + lk);
    f32x4 acc0 = {0.f, 0.f, 0.f, 0.f}, acc1 = acc0, acc2 = acc0, acc3 = acc0;
    const int BS = 2 * K;   // 16 rows * K/8 short8v's
#pragma unroll
    for (int kk = 0; kk < K / 32; ++kk) {
        short8v a = Ap[kk * 4];
        acc0 = __builtin_amdgcn_mfma_f32_16x16x32_bf16(a, Bp[kk * 4], acc0, 0, 0, 0);
        acc1 = __builtin_amdgcn_mfma_f32_16x16x32_bf16(a, Bp[kk * 4 + BS], acc1, 0, 0, 0);
        acc2 = __builtin_amdgcn_mfma_f32_16x16x32_bf16(a, Bp[kk * 4 + 2 * BS], acc2, 0, 0, 0);
        acc3 = __builtin_amdgcn_mfma_f32_16x16x32_bf16(a, Bp[kk * 4 + 3 * BS], acc3, 0, 0, 0);
    }
    int rb = m0 + (l >> 4) * 4;
    int cb = n0 + lm;
    f32x4 accs[4] = {acc0, acc1, acc2, acc3};
#pragma unroll
    for (int j = 0; j < 4; ++j) {
        int c = cb + 16 * j;
#pragma unroll
        for (int r = 0; r < 4; ++r) {
            int row = rb + r;
            if (row < NODES) {
                size_t off = HEADMAJ ? ((size_t)(c >> 7) * NODES + row) * HIDF + (c & 127)
                                     : (size_t)row * NTOT + c;
                Y[off] = bfr(accs[j][r]);
            }
        }
    }
}

// ---------------- GraphConv gather: 1 wave/node, 4 edges in flight, 16B loads ---------
// lane = quarter*16 + q; quarter handles edges i%4==quarter; q owns cols 8q..8q+7
// MODE 1: out = bf16(relu(agg*inv_i + b) * inv_o); MODE 2: + el/er via WL/WR
template<int MODE>
__global__ __launch_bounds__(64)
void gc_gather(const int* __restrict__ rowptr, const int* __restrict__ csr_src,
               const unsigned short* __restrict__ Zb, const float* __restrict__ inv_i,
               const float* __restrict__ inv_o, const float* __restrict__ bias,
               unsigned short* __restrict__ Hb, const float* __restrict__ WL,
               const float* __restrict__ WR, float* __restrict__ el, float* __restrict__ er) {
    int n = blockIdx.x;
    int l = threadIdx.x;
    int quarter = l >> 4, q = l & 15;
    int beg = rowptr[n], end = rowptr[n + 1];
    float a[8] = {0.f, 0.f, 0.f, 0.f, 0.f, 0.f, 0.f, 0.f};
    for (int i = beg + quarter; i < end; i += 4) {
        int s = csr_src[i];
        uint4 z = *(const uint4*)&Zb[s * HIDF + 8 * q];
        a[0] += bf_lo(z.x); a[1] += bf_hi(z.x);
        a[2] += bf_lo(z.y); a[3] += bf_hi(z.y);
        a[4] += bf_lo(z.z); a[5] += bf_hi(z.z);
        a[6] += bf_lo(z.w); a[7] += bf_hi(z.w);
    }
#pragma unroll
    for (int j = 0; j < 8; ++j) {
        a[j] += __shfl_xor(a[j], 16, 64);
        a[j] += __shfl_xor(a[j], 32, 64);
    }
    float sc = inv_i[n];
    float v[8];
#pragma unroll
    for (int j = 0; j < 8; ++j) v[j] = fmaxf(fmaf(a[j], sc, bias[8 * q + j]), 0.f);
    if (l < 16) {
        float so = (MODE == 1) ? inv_o[n] : 1.f;
        uint4 o;
        o.x = ((unsigned)bfr(v[1] * so) << 16) | bfr(v[0] * so);
        o.y = ((unsigned)bfr(v[3] * so) << 16) | bfr(v[2] * so);
        o.z = ((unsigned)bfr(v[5] * so) << 16) | bfr(v[4] * so);
        o.w = ((unsigned)bfr(v[7] * so) << 16) | bfr(v[6] * so);
        *(uint4*)&Hb[n * HIDF + 8 * q] = o;
    }
    if (MODE == 2) {
        float elh[NHEADS] = {0.f, 0.f, 0.f, 0.f};
        float erh[NHEADS] = {0.f, 0.f, 0.f, 0.f};
#pragma unroll
        for (int j = 0; j < 8; ++j) {
            int k = 8 * q + j;
#pragma unroll
            for (int h = 0; h < NHEADS; ++h) {
                elh[h] = fmaf(v[j], WL[k * NHEADS + h], elh[h]);
                erh[h] = fmaf(v[j], WR[k * NHEADS + h], erh[h]);
            }
        }
        // reduce over q only (quarters hold duplicates): offsets 1..8
#pragma unroll
        for (int h = 0; h < NHEADS; ++h) {
#pragma unroll
            for (int off = 1; off <= 8; off <<= 1) {
                elh[h] += __shfl_xor(elh[h], off, 64);
                erh[h] += __shfl_xor(erh[h], off, 64);
            }
        }
        if (l == 0) {
#pragma unroll
            for (int h = 0; h < NHEADS; ++h) {
                el[n * NHEADS + h] = elh[h];
                er[n * NHEADS + h] = erh[h];
            }
        }
    }
}

// ---------------- fused GAT: 1 wave/(node,head); LDS (src,ex) pairs; 4 edges in flight
__global__ __launch_bounds__(64)
void gat_fused(const int* __restrict__ rowptr, const int* __restrict__ csr_src,
               const float* __restrict__ el, const float* __restrict__ er,
               const unsigned short* __restrict__ Zg /*[4][NODES][128]*/,
               const float* __restrict__ w3, float* __restrict__ ps) {
    __shared__ int2 se[128];
    int x = blockIdx.x;
    int h = (x & 7) >> 1;                    // heads pinned to XCD pairs
    int n = ((x >> 3) << 1) | (x & 1);
    int l = threadIdx.x;
    int beg = rowptr[n], end = rowptr[n + 1];
    int deg = end - beg;
    float ern = er[n * NHEADS + h];
    int i0 = beg + l, i1 = beg + 64 + l;
    int s0 = 0, s1 = 0;
    float lg0 = -1e30f, lg1 = -1e30f;
    if (i0 < end) {
        s0 = csr_src[i0];
        float t = el[s0 * NHEADS + h] + ern;
        lg0 = t > 0.f ? t : 0.2f * t;
    }
    if (i1 < end) {
        s1 = csr_src[i1];
        float t = el[s1 * NHEADS + h] + ern;
        lg1 = t > 0.f ? t : 0.2f * t;
    }
    float m = fmaxf(lg0, lg1);
#pragma unroll
    for (int off = 32; off; off >>= 1) m = fmaxf(m, __shfl_xor(m, off, 64));
    float ex0 = (i0 < end) ? __expf(lg0 - m) : 0.f;
    float ex1 = (i1 < end) ? __expf(lg1 - m) : 0.f;
    float den = ex0 + ex1;
#pragma unroll
    for (int off = 32; off; off >>= 1) den += __shfl_xor(den, off, 64);
    se[l] = make_int2(s0, __float_as_int(ex0));
    se[64 + l] = make_int2(s1, __float_as_int(ex1));
    __syncthreads();
    int quarter = l >> 4, q = l & 15;
    const unsigned short* Zh = Zg + (size_t)h * NODES * HIDF;
    float a[8] = {0.f, 0.f, 0.f, 0.f, 0.f, 0.f, 0.f, 0.f};
    for (int ii = quarter; ii < deg; ii += 4) {
        int2 p = se[ii];
        float ev = __int_as_float(p.y);
        uint4 z = *(const uint4*)&Zh[(size_t)p.x * HIDF + 8 * q];
        a[0] = fmaf(ev, bf_lo(z.x), a[0]); a[1] = fmaf(ev, bf_hi(z.x), a[1]);
        a[2] = fmaf(ev, bf_lo(z.y), a[2]); a[3] = fmaf(ev, bf_hi(z.y), a[3]);
        a[4] = fmaf(ev, bf_lo(z.z), a[4]); a[5] = fmaf(ev, bf_hi(z.z), a[5]);
        a[6] = fmaf(ev, bf_lo(z.w), a[6]); a[7] = fmaf(ev, bf_hi(z.w), a[7]);
    }
#pragma unroll
    for (int j = 0; j < 8; ++j) {
        a[j] += __shfl_xor(a[j], 16, 64);
        a[j] += __shfl_xor(a[j], 32, 64);
    }
    float pd = 0.f;
#pragma unroll
    for (int j = 0; j < 8; ++j) pd = fmaf(a[j], w3[8 * q + j], pd);
#pragma unroll
    for (int off = 1; off <= 8; off <<= 1) pd += __shfl_xor(pd, off, 64);
    if (l == 0) ps[n * NHEADS + h] = den > 0.f ? pd / den : 0.f;
}

// ------- GC3 gather + sigmoid: 1 wave/node; s1[src] computed inline from ps --------
__global__ __launch_bounds__(64)
void gc3_gather(const int* __restrict__ rowptr, const int* __restrict__ csr_src,
                const float* __restrict__ ps, const float* __restrict__ inv_o,
                const float* __restrict__ cdot, const float* __restrict__ inv_i,
                const float* __restrict__ b3, float* __restrict__ out) {
    int n = blockIdx.x;
    int l = threadIdx.x;
    int beg = rowptr[n], end = rowptr[n + 1];
    float cd = cdot[0];
    float acc = 0.f;
    for (int i = beg + l; i < end; i += 64) {
        int s = csr_src[i];
        float4 p = ((const float4*)ps)[s];
        acc += inv_o[s] * (0.25f * (p.x + p.y + p.z + p.w) + cd);
    }
#pragma unroll
    for (int off = 32; off; off >>= 1) acc += __shfl_xor(acc, off, 64);
    if (l == 0) {
        float xv = acc * inv_i[n] + b3[0];
        out[n] = 1.f / (1.f + __expf(-xv));
    }
}

extern "C" void kernel_launch(void* const* d_in, const int* in_sizes, int n_in,
                              void* d_out, int out_size, void* d_ws, size_t ws_size,
                              hipStream_t stream) {
    const float* feat   = (const float*)d_in[0];
    const int*   src    = (const int*)d_in[1];
    const int*   dst    = (const int*)d_in[2];
    const float* W1     = (const float*)d_in[3];
    const float* b1     = (const float*)d_in[4];
    const float* W2     = (const float*)d_in[5];
    const float* b2     = (const float*)d_in[6];
    const float* W3     = (const float*)d_in[7];
    const float* b3     = (const float*)d_in[8];
    const float* Wg     = (const float*)d_in[9];
    const float* attn_l = (const float*)d_in[10];
    const float* attn_r = (const float*)d_in[11];
    const float* bg     = (const float*)d_in[12];

    char* w = (char*)d_ws;
    auto alloc = [&](size_t bytes) { void* p = (void*)w; w += (bytes + 255) & ~(size_t)255; return p; };
    int*   deg     = (int*)  alloc(2 * NODES * 4);   // deg_o | deg_i contiguous
    int*   deg_o   = deg;
    int*   deg_i   = deg + NODES;
    float* inv_o   = (float*)alloc(NODES * 4);
    float* inv_i   = (float*)alloc(NODES * 4);
    int*   rowptr  = (int*)  alloc((NODES + 1) * 4);
    int*   cursor  = (int*)  alloc(NODES * 4);
    int*   csr_src = (int*)  alloc((size_t)EDGES * 4);
    unsigned short* W1t = (unsigned short*)alloc(128 * 256 * 2);
    unsigned short* W2t = (unsigned short*)alloc(128 * 128 * 2);
    unsigned short* Wgt = (unsigned short*)alloc(512 * 128 * 2);
    float* WL      = (float*)alloc(HIDF * NHEADS * 4);
    float* WR      = (float*)alloc(HIDF * NHEADS * 4);
    float* cdot    = (float*)alloc(256);
    float* el      = (float*)alloc(NODES * NHEADS * 4);
    float* er      = (float*)alloc(NODES * NHEADS * 4);
    float* ps      = (float*)alloc(NODES * NHEADS * 4);
    unsigned short* Abf = (unsigned short*)alloc((size_t)NODES * INF_ * 2);
    unsigned short* Zb  = (unsigned short*)alloc((size_t)NODES * HIDF * 2);
    unsigned short* H1b = (unsigned short*)alloc((size_t)NODES * HIDF * 2);
    unsigned short* H2b = (unsigned short*)alloc((size_t)NODES * HIDF * 2);
    unsigned short* Zg  = (unsigned short*)alloc((size_t)NHEADS * NODES * HIDF * 2);

    // ---- prep (also zeroes degree arrays; runs before deg_kernel in stream order) ----
    prep0<<<WPREP_BLKS + 1 + DEGZ_BLKS, 512, 0, stream>>>(W1, W2, Wg, attn_l, attn_r, bg,
                                                          W3, W1t, W2t, Wgt, WL, WR, cdot,
                                                          deg);
    deg_kernel<<<EDGE_BLKS, 256, 0, stream>>>(src, dst, deg_o, deg_i);
    scan_inv<<<1, SCAN_T, 0, stream>>>(deg_i, deg_o, rowptr, cursor, inv_o, inv_i);
    post_scan<<<EDGE_BLKS + FEAT_BLKS, 256, 0, stream>>>(src, dst, cursor, csr_src,
                                                         feat, inv_o, Abf);

    // ---- GraphConv 1 ----
    mfma_gemm<INF_, 0><<<dim3((NODES + 63) / 64, 2), 256, 0, stream>>>(Abf, W1t, Zb, HIDF);
    gc_gather<1><<<NODES, 64, 0, stream>>>(rowptr, csr_src, Zb, inv_i, inv_o, b1,
                                           H1b, nullptr, nullptr, nullptr, nullptr);

    // ---- GraphConv 2 (+ el/er epilogue) ----
    mfma_gemm<HIDF, 0><<<dim3((NODES + 63) / 64, 2), 256, 0, stream>>>(H1b, W2t, Zb, HIDF);
    gc_gather<2><<<NODES, 64, 0, stream>>>(rowptr, csr_src, Zb, inv_i, inv_o, b2,
                                           H2b, WL, WR, el, er);

    // ---- GAT ----
    mfma_gemm<HIDF, 1><<<dim3((NODES + 63) / 64, 8), 256, 0, stream>>>(H2b, Wgt, Zg, NHEADS * HIDF);
    gat_fused<<<NODES * NHEADS, 64, 0, stream>>>(rowptr, csr_src, el, er, Zg, W3, ps);

    // ---- GC3 (s1 inlined) ----
    gc3_gather<<<NODES, 64, 0, stream>>>(rowptr, csr_src, ps, inv_o, cdot, inv_i, b3,
                                         (float*)d_out);
}

// Round 8
// 189.945 us; speedup vs baseline: 5.5730x; 1.1446x over previous
//
#include <hip/hip_runtime.h>
#include <hip/hip_bf16.h>

#define NODES   10000
#define EDGES   320000
#define INF_    256
#define HIDF    128
#define NHEADS  4
#define SCAN_T  1024
#define SCAN_C  10
#define EDGE_BLKS  ((EDGES + 255) / 256)          // 1250
#define FEAT_ITEMS (NODES * (INF_ / 4))           // 640000 float4's
#define FEAT_BLKS  ((FEAT_ITEMS + 255) / 256)     // 2500
#define WPREP_ITEMS (128 * 256 + 128 * 128)       // 49152 (W1t + W2t)
#define WPREP_BLKS  (WPREP_ITEMS / 512)           // 96
#define DEGZ_BLKS  ((2 * NODES + 511) / 512)      // 40

typedef __attribute__((ext_vector_type(8))) short short8v;   // 8 bf16
typedef __attribute__((ext_vector_type(4))) float f32x4;

__device__ __forceinline__ float bf_lo(unsigned z) { return __uint_as_float(z << 16); }
__device__ __forceinline__ float bf_hi(unsigned z) { return __uint_as_float(z & 0xffff0000u); }
__device__ __forceinline__ unsigned short bfr(float x) {
    __hip_bfloat16 b = __float2bfloat16(x);
    return *(unsigned short*)&b;
}

// ---------------- degree ----------------
__global__ void deg_kernel(const int* __restrict__ src, const int* __restrict__ dst,
                           int* __restrict__ deg_o, int* __restrict__ deg_i) {
    int e = blockIdx.x * blockDim.x + threadIdx.x;
    if (e < EDGES) {
        atomicAdd(&deg_o[src[e]], 1);
        atomicAdd(&deg_i[dst[e]], 1);
    }
}

// ---------------- scan of deg_i -> rowptr/cursor, plus inv norms ----------------
__global__ void scan_inv(const int* __restrict__ deg_i, const int* __restrict__ deg_o,
                         int* __restrict__ rowptr, int* __restrict__ cursor,
                         float* __restrict__ inv_o, float* __restrict__ inv_i) {
    __shared__ int part[SCAN_T];
    int t = threadIdx.x;
    int base = t * SCAN_C;
    int local[SCAN_C];
    int s = 0;
    for (int j = 0; j < SCAN_C; ++j) {
        int idx = base + j;
        int v = idx < NODES ? deg_i[idx] : 0;
        local[j] = s;
        s += v;
    }
    part[t] = s;
    __syncthreads();
    for (int off = 1; off < SCAN_T; off <<= 1) {
        int v = (t >= off) ? part[t - off] : 0;
        __syncthreads();
        part[t] += v;
        __syncthreads();
    }
    int offs = (t > 0) ? part[t - 1] : 0;
    for (int j = 0; j < SCAN_C; ++j) {
        int idx = base + j;
        if (idx < NODES) {
            int r = offs + local[j];
            rowptr[idx] = r;
            cursor[idx] = r;
            inv_i[idx] = rsqrtf(fmaxf((float)deg_i[idx], 1.0f));
            inv_o[idx] = rsqrtf(fmaxf((float)deg_o[idx], 1.0f));
        }
    }
    if (t == SCAN_T - 1) rowptr[NODES] = part[SCAN_T - 1];
}

// ---- prep0: bf16 transposed weights + folded attn/W3 vectors + cdot + zero degrees ----
// WL/WR[k][h] = Wg[k,:]_h . attn_{l,r}[h];  WV[k][h] = Wg[k,:]_h . W3
__global__ __launch_bounds__(512)
void prep0(const float* __restrict__ W1, const float* __restrict__ W2,
           const float* __restrict__ Wg, const float* __restrict__ attn_l,
           const float* __restrict__ attn_r, const float* __restrict__ bg,
           const float* __restrict__ W3, unsigned short* __restrict__ W1t,
           unsigned short* __restrict__ W2t, float* __restrict__ WL,
           float* __restrict__ WR, float* __restrict__ WV, float* __restrict__ cdot,
           int* __restrict__ deg) {
    int b = blockIdx.x;
    if (b < WPREP_BLKS) {
        int id = b * 512 + threadIdx.x;
        if (id < 128 * 256) {                 // W1 [256][128] -> W1t [128][256]
            int nn = id >> 8, k = id & 255;
            W1t[id] = bfr(W1[k * HIDF + nn]);
        } else {                              // W2 [128][128] -> W2t [128][128]
            id -= 128 * 256;
            int nn = id >> 7, k = id & 127;
            W2t[id] = bfr(W2[k * HIDF + nn]);
        }
        return;
    }
    if (b > WPREP_BLKS) {                     // zero deg_o|deg_i (2*NODES ints)
        int id = (b - WPREP_BLKS - 1) * 512 + threadIdx.x;
        if (id < 2 * NODES) deg[id] = 0;
        return;
    }
    // fold block (b == WPREP_BLKS)
    __shared__ float red[HIDF];
    int id = threadIdx.x;  // 512
    int k = id >> 2, h = id & 3;
    float a = 0.f, bb = 0.f, c = 0.f;
    for (int d = 0; d < HIDF; ++d) {
        float w = Wg[k * 512 + h * HIDF + d];
        a = fmaf(w, attn_l[h * HIDF + d], a);
        bb = fmaf(w, attn_r[h * HIDF + d], bb);
        c = fmaf(w, W3[d], c);
    }
    WL[id] = a;
    WR[id] = bb;
    WV[id] = c;
    if (id < HIDF) red[id] = (bg[id] + bg[id + 128] + bg[id + 256] + bg[id + 384]) * W3[id];
    __syncthreads();
    if (id == 0) {
        float s = 0.f;
        for (int t = 0; t < HIDF; ++t) s += red[t];
        cdot[0] = 0.25f * s;
    }
}

// ---------------- post_scan: csr_fill + feat->bf16*inv_o ----------------
__global__ void post_scan(const int* __restrict__ src, const int* __restrict__ dst,
                          int* __restrict__ cursor, int* __restrict__ csr_src,
                          const float* __restrict__ feat, const float* __restrict__ inv_o,
                          unsigned short* __restrict__ Abf) {
    int b = blockIdx.x;
    if (b < EDGE_BLKS) {
        int e = b * 256 + threadIdx.x;
        if (e < EDGES) {
            int pos = atomicAdd(&cursor[dst[e]], 1);
            csr_src[pos] = src[e];
        }
    } else {
        int id = (b - EDGE_BLKS) * 256 + threadIdx.x;
        if (id < FEAT_ITEMS) {
            int n = id >> 6;                  // /(INF_/4)
            float4 v = ((const float4*)feat)[id];
            float s = inv_o[n];
            uint2 o;
            o.x = ((unsigned)bfr(v.y * s) << 16) | bfr(v.x * s);
            o.y = ((unsigned)bfr(v.w * s) << 16) | bfr(v.z * s);
            ((uint2*)Abf)[id] = o;
        }
    }
}

// ---------------- MFMA GEMM: Y = A[M,K] @ Bt[N,K]^T, bf16; 64x64 block, 4 acc/wave ----
template<int K>
__global__ __launch_bounds__(256)
void mfma_gemm(const unsigned short* __restrict__ A, const unsigned short* __restrict__ Bt,
               unsigned short* __restrict__ Y, int NTOT) {
    int w = threadIdx.x >> 6, l = threadIdx.x & 63;
    int m0 = blockIdx.x * 64 + w * 16;
    int n0 = blockIdx.y * 64;
    int lm = l & 15, lk = (l >> 4) * 8;
    int arow = min(m0 + lm, NODES - 1);
    const short8v* Ap = (const short8v*)(A + (size_t)arow * K + lk);
    const short8v* Bp = (const short8v*)(Bt + (size_t)(n0 + lm) * K + lk);
    f32x4 acc0 = {0.f, 0.f, 0.f, 0.f}, acc1 = acc0, acc2 = acc0, acc3 = acc0;
    const int BS = 2 * K;   // 16 rows * K/8 short8v's
#pragma unroll
    for (int kk = 0; kk < K / 32; ++kk) {
        short8v a = Ap[kk * 4];
        acc0 = __builtin_amdgcn_mfma_f32_16x16x32_bf16(a, Bp[kk * 4], acc0, 0, 0, 0);
        acc1 = __builtin_amdgcn_mfma_f32_16x16x32_bf16(a, Bp[kk * 4 + BS], acc1, 0, 0, 0);
        acc2 = __builtin_amdgcn_mfma_f32_16x16x32_bf16(a, Bp[kk * 4 + 2 * BS], acc2, 0, 0, 0);
        acc3 = __builtin_amdgcn_mfma_f32_16x16x32_bf16(a, Bp[kk * 4 + 3 * BS], acc3, 0, 0, 0);
    }
    int rb = m0 + (l >> 4) * 4;
    int cb = n0 + lm;
    f32x4 accs[4] = {acc0, acc1, acc2, acc3};
#pragma unroll
    for (int j = 0; j < 4; ++j) {
        int c = cb + 16 * j;
#pragma unroll
        for (int r = 0; r < 4; ++r) {
            int row = rb + r;
            if (row < NODES) Y[(size_t)row * NTOT + c] = bfr(accs[j][r]);
        }
    }
}

// ---------------- GraphConv gather: 1 wave/node, 4 edges in flight, 16B loads ---------
// lane = quarter*16 + q; quarter handles edges i%4==quarter; q owns cols 8q..8q+7
// MODE 1: Hb = bf16(relu(agg*inv_i + b) * inv_o)   (feeds next GEMM)
// MODE 2: no Hb; writes el4/er4/zeta4 via folded WL/WR/WV   (feeds GAT)
template<int MODE>
__global__ __launch_bounds__(64)
void gc_gather(const int* __restrict__ rowptr, const int* __restrict__ csr_src,
               const unsigned short* __restrict__ Zb, const float* __restrict__ inv_i,
               const float* __restrict__ inv_o, const float* __restrict__ bias,
               unsigned short* __restrict__ Hb, const float* __restrict__ WL,
               const float* __restrict__ WR, const float* __restrict__ WV,
               float* __restrict__ el, float* __restrict__ er, float* __restrict__ zeta) {
    int n = blockIdx.x;
    int l = threadIdx.x;
    int quarter = l >> 4, q = l & 15;
    int beg = rowptr[n], end = rowptr[n + 1];
    float a[8] = {0.f, 0.f, 0.f, 0.f, 0.f, 0.f, 0.f, 0.f};
#pragma unroll 2
    for (int i = beg + quarter; i < end; i += 4) {
        int s = csr_src[i];
        uint4 z = *(const uint4*)&Zb[s * HIDF + 8 * q];
        a[0] += bf_lo(z.x); a[1] += bf_hi(z.x);
        a[2] += bf_lo(z.y); a[3] += bf_hi(z.y);
        a[4] += bf_lo(z.z); a[5] += bf_hi(z.z);
        a[6] += bf_lo(z.w); a[7] += bf_hi(z.w);
    }
#pragma unroll
    for (int j = 0; j < 8; ++j) {
        a[j] += __shfl_xor(a[j], 16, 64);
        a[j] += __shfl_xor(a[j], 32, 64);
    }
    float sc = inv_i[n];
    float v[8];
#pragma unroll
    for (int j = 0; j < 8; ++j) v[j] = fmaxf(fmaf(a[j], sc, bias[8 * q + j]), 0.f);
    if (MODE == 1) {
        if (l < 16) {
            float so = inv_o[n];
            uint4 o;
            o.x = ((unsigned)bfr(v[1] * so) << 16) | bfr(v[0] * so);
            o.y = ((unsigned)bfr(v[3] * so) << 16) | bfr(v[2] * so);
            o.z = ((unsigned)bfr(v[5] * so) << 16) | bfr(v[4] * so);
            o.w = ((unsigned)bfr(v[7] * so) << 16) | bfr(v[6] * so);
            *(uint4*)&Hb[n * HIDF + 8 * q] = o;
        }
    }
    if (MODE == 2) {
        float elh[NHEADS] = {0.f, 0.f, 0.f, 0.f};
        float erh[NHEADS] = {0.f, 0.f, 0.f, 0.f};
        float zth[NHEADS] = {0.f, 0.f, 0.f, 0.f};
#pragma unroll
        for (int j = 0; j < 8; ++j) {
            int k = 8 * q + j;
#pragma unroll
            for (int h = 0; h < NHEADS; ++h) {
                elh[h] = fmaf(v[j], WL[k * NHEADS + h], elh[h]);
                erh[h] = fmaf(v[j], WR[k * NHEADS + h], erh[h]);
                zth[h] = fmaf(v[j], WV[k * NHEADS + h], zth[h]);
            }
        }
        // reduce over q (quarters hold duplicates): offsets 1..8
#pragma unroll
        for (int h = 0; h < NHEADS; ++h) {
#pragma unroll
            for (int off = 1; off <= 8; off <<= 1) {
                elh[h] += __shfl_xor(elh[h], off, 64);
                erh[h] += __shfl_xor(erh[h], off, 64);
                zth[h] += __shfl_xor(zth[h], off, 64);
            }
        }
        if (l == 0) {
#pragma unroll
            for (int h = 0; h < NHEADS; ++h) {
                el[n * NHEADS + h] = elh[h];
                er[n * NHEADS + h] = erh[h];
                zeta[n * NHEADS + h] = zth[h];
            }
        }
    }
}

// ---- GAT collapsed: 1 wave/node, all 4 heads as float4, scalar zeta aggregation ----
// s1v[n] = inv_o[n]*(0.25*sum_h (sum_i ex_i*zeta[s_i,h])/den_h + cdot)
__global__ __launch_bounds__(64)
void gat_s1(const int* __restrict__ rowptr, const int* __restrict__ csr_src,
            const float4* __restrict__ el4, const float4* __restrict__ er4,
            const float4* __restrict__ zeta4, const float* __restrict__ inv_o,
            const float* __restrict__ cdot, float* __restrict__ s1v) {
    int n = blockIdx.x;
    int l = threadIdx.x;
    int beg = rowptr[n], end = rowptr[n + 1];
    float4 ern = er4[n];
    int i0 = beg + l, i1 = beg + 64 + l;
    float lg0[4] = {-1e30f, -1e30f, -1e30f, -1e30f};
    float lg1[4] = {-1e30f, -1e30f, -1e30f, -1e30f};
    float zt0[4] = {0.f, 0.f, 0.f, 0.f}, zt1[4] = {0.f, 0.f, 0.f, 0.f};
    if (i0 < end) {
        int s = csr_src[i0];
        float4 e = el4[s], z = zeta4[s];
        float t;
        t = e.x + ern.x; lg0[0] = t > 0.f ? t : 0.2f * t; zt0[0] = z.x;
        t = e.y + ern.y; lg0[1] = t > 0.f ? t : 0.2f * t; zt0[1] = z.y;
        t = e.z + ern.z; lg0[2] = t > 0.f ? t : 0.2f * t; zt0[2] = z.z;
        t = e.w + ern.w; lg0[3] = t > 0.f ? t : 0.2f * t; zt0[3] = z.w;
    }
    if (i1 < end) {
        int s = csr_src[i1];
        float4 e = el4[s], z = zeta4[s];
        float t;
        t = e.x + ern.x; lg1[0] = t > 0.f ? t : 0.2f * t; zt1[0] = z.x;
        t = e.y + ern.y; lg1[1] = t > 0.f ? t : 0.2f * t; zt1[1] = z.y;
        t = e.z + ern.z; lg1[2] = t > 0.f ? t : 0.2f * t; zt1[2] = z.z;
        t = e.w + ern.w; lg1[3] = t > 0.f ? t : 0.2f * t; zt1[3] = z.w;
    }
    float m[4], den[4], acc[4];
#pragma unroll
    for (int h = 0; h < 4; ++h) m[h] = fmaxf(lg0[h], lg1[h]);
#pragma unroll
    for (int off = 32; off; off >>= 1)
#pragma unroll
        for (int h = 0; h < 4; ++h) m[h] = fmaxf(m[h], __shfl_xor(m[h], off, 64));
#pragma unroll
    for (int h = 0; h < 4; ++h) {
        float e0 = (i0 < end) ? __expf(lg0[h] - m[h]) : 0.f;
        float e1 = (i1 < end) ? __expf(lg1[h] - m[h]) : 0.f;
        den[h] = e0 + e1;
        acc[h] = e0 * zt0[h] + e1 * zt1[h];
    }
#pragma unroll
    for (int off = 32; off; off >>= 1)
#pragma unroll
        for (int h = 0; h < 4; ++h) {
            den[h] += __shfl_xor(den[h], off, 64);
            acc[h] += __shfl_xor(acc[h], off, 64);
        }
    if (l == 0) {
        float s = 0.f;
#pragma unroll
        for (int h = 0; h < 4; ++h) s += den[h] > 0.f ? acc[h] / den[h] : 0.f;
        s1v[n] = inv_o[n] * (0.25f * s + cdot[0]);
    }
}

// ---------------- GC3 gather + sigmoid: 1 wave/node ----------------
__global__ __launch_bounds__(64)
void gc3_gather(const int* __restrict__ rowptr, const int* __restrict__ csr_src,
                const float* __restrict__ s1v, const float* __restrict__ inv_i,
                const float* __restrict__ b3, float* __restrict__ out) {
    int n = blockIdx.x;
    int l = threadIdx.x;
    int beg = rowptr[n], end = rowptr[n + 1];
    float acc = 0.f;
    for (int i = beg + l; i < end; i += 64) acc += s1v[csr_src[i]];
#pragma unroll
    for (int off = 32; off; off >>= 1) acc += __shfl_xor(acc, off, 64);
    if (l == 0) {
        float xv = acc * inv_i[n] + b3[0];
        out[n] = 1.f / (1.f + __expf(-xv));
    }
}

extern "C" void kernel_launch(void* const* d_in, const int* in_sizes, int n_in,
                              void* d_out, int out_size, void* d_ws, size_t ws_size,
                              hipStream_t stream) {
    const float* feat   = (const float*)d_in[0];
    const int*   src    = (const int*)d_in[1];
    const int*   dst    = (const int*)d_in[2];
    const float* W1     = (const float*)d_in[3];
    const float* b1     = (const float*)d_in[4];
    const float* W2     = (const float*)d_in[5];
    const float* b2     = (const float*)d_in[6];
    const float* W3     = (const float*)d_in[7];
    const float* b3     = (const float*)d_in[8];
    const float* Wg     = (const float*)d_in[9];
    const float* attn_l = (const float*)d_in[10];
    const float* attn_r = (const float*)d_in[11];
    const float* bg     = (const float*)d_in[12];

    char* w = (char*)d_ws;
    auto alloc = [&](size_t bytes) { void* p = (void*)w; w += (bytes + 255) & ~(size_t)255; return p; };
    int*   deg     = (int*)  alloc(2 * NODES * 4);   // deg_o | deg_i contiguous
    int*   deg_o   = deg;
    int*   deg_i   = deg + NODES;
    float* inv_o   = (float*)alloc(NODES * 4);
    float* inv_i   = (float*)alloc(NODES * 4);
    int*   rowptr  = (int*)  alloc((NODES + 1) * 4);
    int*   cursor  = (int*)  alloc(NODES * 4);
    int*   csr_src = (int*)  alloc((size_t)EDGES * 4);
    unsigned short* W1t = (unsigned short*)alloc(128 * 256 * 2);
    unsigned short* W2t = (unsigned short*)alloc(128 * 128 * 2);
    float* WL      = (float*)alloc(HIDF * NHEADS * 4);
    float* WR      = (float*)alloc(HIDF * NHEADS * 4);
    float* WV      = (float*)alloc(HIDF * NHEADS * 4);
    float* cdot    = (float*)alloc(256);
    float* el      = (float*)alloc(NODES * NHEADS * 4);
    float* er      = (float*)alloc(NODES * NHEADS * 4);
    float* zeta    = (float*)alloc(NODES * NHEADS * 4);
    float* s1v     = (float*)alloc(NODES * 4);
    unsigned short* Abf = (unsigned short*)alloc((size_t)NODES * INF_ * 2);
    unsigned short* Zb  = (unsigned short*)alloc((size_t)NODES * HIDF * 2);
    unsigned short* H1b = (unsigned short*)alloc((size_t)NODES * HIDF * 2);

    // ---- prep (also zeroes degree arrays; runs before deg_kernel in stream order) ----
    prep0<<<WPREP_BLKS + 1 + DEGZ_BLKS, 512, 0, stream>>>(W1, W2, Wg, attn_l, attn_r, bg,
                                                          W3, W1t, W2t, WL, WR, WV, cdot,
                                                          deg);
    deg_kernel<<<EDGE_BLKS, 256, 0, stream>>>(src, dst, deg_o, deg_i);
    scan_inv<<<1, SCAN_T, 0, stream>>>(deg_i, deg_o, rowptr, cursor, inv_o, inv_i);
    post_scan<<<EDGE_BLKS + FEAT_BLKS, 256, 0, stream>>>(src, dst, cursor, csr_src,
                                                         feat, inv_o, Abf);

    // ---- GraphConv 1 ----
    mfma_gemm<INF_><<<dim3((NODES + 63) / 64, 2), 256, 0, stream>>>(Abf, W1t, Zb, HIDF);
    gc_gather<1><<<NODES, 64, 0, stream>>>(rowptr, csr_src, Zb, inv_i, inv_o, b1, H1b,
                                           nullptr, nullptr, nullptr, nullptr, nullptr,
                                           nullptr);

    // ---- GraphConv 2 (epilogue computes el/er/zeta; H2 never materialized) ----
    mfma_gemm<HIDF><<<dim3((NODES + 63) / 64, 2), 256, 0, stream>>>(H1b, W2t, Zb, HIDF);
    gc_gather<2><<<NODES, 64, 0, stream>>>(rowptr, csr_src, Zb, inv_i, inv_o, b2, nullptr,
                                           WL, WR, WV, el, er, zeta);

    // ---- GAT collapsed to scalar-zeta aggregation -> s1 ----
    gat_s1<<<NODES, 64, 0, stream>>>(rowptr, csr_src, (const float4*)el, (const float4*)er,
                                     (const float4*)zeta, inv_o, cdot, s1v);

    // ---- GC3 ----
    gc3_gather<<<NODES, 64, 0, stream>>>(rowptr, csr_src, s1v, inv_i, b3, (float*)d_out);
}